// Round 7
// baseline (617.888 us; speedup 1.0000x reference)
//
#include <hip/hip_runtime.h>
#include <hip/hip_bf16.h>

typedef __hip_bfloat16 bf16;

static __device__ __forceinline__ float b2f(bf16 v) { return __bfloat162float(v); }

// flag-aware input load: bf==1 -> bf16, bf==0 -> f32
static __device__ __forceinline__ float ldin(const void* p, long i, int bf) {
    return bf ? b2f(((const bf16*)p)[i]) : ((const float*)p)[i];
}

// ---------------- dtype detect ----------------
__global__ void detect_k(const unsigned short* __restrict__ x16, int* __restrict__ flag) {
    __shared__ int cnt[256];
    unsigned short u = x16[threadIdx.x];
    int e = (u >> 7) & 0xFF;
    cnt[threadIdx.x] = (e >= 100 && e <= 140) ? 1 : 0;
    __syncthreads();
    for (int off = 128; off > 0; off >>= 1) {
        if (threadIdx.x < off) cnt[threadIdx.x] += cnt[threadIdx.x + off];
        __syncthreads();
    }
    if (threadIdx.x == 0) *flag = (cnt[0] > 217) ? 1 : 0;
}

// ---------------- transposes ----------------
__global__ void transpose_w_k(const void* __restrict__ in, float* __restrict__ out,
                              int M, int K, const int* __restrict__ flagp) {
    int bf = *flagp;
    int idx = blockIdx.x * 256 + threadIdx.x;
    if (idx >= M * K) return;
    int k = idx / M, m = idx - k * M;
    out[idx] = ldin(in, (long)m * K + k, bf);
}

// out[(n*256 + c)*512 + h3] = w3[(h3*256 + c)*32 + n]
__global__ void transpose_w3_k(const void* __restrict__ w3, float* __restrict__ out,
                               const int* __restrict__ flagp) {
    int bf = *flagp;
    int bid = blockIdx.x;            // 2048 = 8 h3-tiles * 256 c
    int h30 = (bid & 7) * 64;
    int c = bid >> 3;
    __shared__ float tile[64][33];
    int tid = threadIdx.x;
    for (int i = tid; i < 64 * 32; i += 256) {
        int hl = i >> 5, n = i & 31;
        tile[hl][n] = ldin(w3, ((long)(h30 + hl) * 256 + c) * 32 + n, bf);
    }
    __syncthreads();
    for (int i = tid; i < 64 * 32; i += 256) {
        int n = i >> 6, hl = i & 63;
        out[((long)n * 256 + c) * 512 + h30 + hl] = tile[hl][n];
    }
}

// ---------------- im2col ----------------
__global__ void im2col_x_k(const void* __restrict__ x, float* __restrict__ colx,
                           const int* __restrict__ flagp) {
    int bf = *flagp;
    int idx = blockIdx.x * 256 + threadIdx.x;   // 786432
    if (idx >= 786432) return;
    int t = idx & 255;
    int b = idx / 393216;
    int k = (idx - b * 393216) >> 8;
    int c = k / 3, q = k - c * 3;
    int tt = t + q - 1;
    colx[idx] = (tt >= 0 && tt < 256) ? ldin(x, ((long)b * 512 + c) * 256 + tt, bf) : 0.f;
}

__global__ void im2col_f_k(const float* __restrict__ f, float* __restrict__ col) {
    int idx = blockIdx.x * 256 + threadIdx.x;   // 4718592
    if (idx >= 4718592) return;
    int p = idx & 2047;
    int rem = idx >> 11;
    int b = rem / 1152;
    int k = rem - b * 1152;
    int c = k / 9, q = k - c * 9;
    int dy = q / 3, dx = q - dy * 3;
    int t = p >> 3, w = p & 7;
    int tt = t + dy - 1, ww = w + dx - 1;
    col[idx] = (tt >= 0 && tt < 256 && ww >= 0 && ww < 8)
                   ? f[((long)b * 128 + c) * 2048 + tt * 8 + ww] : 0.f;
}

// ---------------- generic tiled GEMM w/ register prefetch ----------------
// C[z][m][p] = bias[m] + sum_k A[za][k][m] * B[zb][k][p]
template<int BM, int BP, int TM, int TP>
__global__ __launch_bounds__(256) void gemm_t(
    const float* __restrict__ A, const float* __restrict__ B, float* __restrict__ C,
    const void* __restrict__ bias, const void* __restrict__ bias2,
    int M, int K, int P, int az_mod, int bz_div,
    long a_zs, long b_zs, long c_zs1, long c_zs2, int c_ms,
    int zmod, int ksplit, int accum, const int* __restrict__ flagp)
{
    int bf = *flagp;
    int zraw = blockIdx.z;
    int z = zraw % zmod;
    int ks = zraw / zmod;
    int klen = K / ksplit;
    int kbeg = ks * klen;
    int kend = kbeg + klen;
    int za = z % az_mod;
    const float* A2 = A + (long)za * a_zs;
    const float* B2 = B + (long)(z / bz_div) * b_zs;
    float* C2 = C + (long)(z / bz_div) * c_zs1 + (long)za * c_zs2;
    const void* bi = (bias2 != nullptr && za != 0) ? bias2 : bias;

    __shared__ float As[16][BM];
    __shared__ float Bs[16][BP];
    int tid = threadIdx.x;
    int ty = tid >> 4, tx = tid & 15;
    int lk = tid >> 4;
    int lma = (tid & 15) * TM;
    int lpb = (tid & 15) * TP;
    int m0 = blockIdx.y * BM, p0 = blockIdx.x * BP;

    float acc[TM][TP];
    #pragma unroll
    for (int i = 0; i < TM; ++i)
        #pragma unroll
        for (int j = 0; j < TP; ++j) acc[i][j] = 0.f;

    float ra[TM], rb[TP];
    {
        const float* ap = A2 + (long)(kbeg + lk) * M + m0 + lma;
        const float* bp = B2 + (long)(kbeg + lk) * P + p0 + lpb;
        #pragma unroll
        for (int u = 0; u < TM; ++u) ra[u] = ap[u];
        #pragma unroll
        for (int u = 0; u < TP; ++u) rb[u] = bp[u];
    }

    for (int kc = kbeg; kc < kend; kc += 16) {
        #pragma unroll
        for (int u = 0; u < TM; ++u) As[lk][lma + u] = ra[u];
        #pragma unroll
        for (int u = 0; u < TP; ++u) Bs[lk][lpb + u] = rb[u];
        __syncthreads();
        if (kc + 16 < kend) {     // prefetch next chunk into registers
            const float* ap = A2 + (long)(kc + 16 + lk) * M + m0 + lma;
            const float* bp = B2 + (long)(kc + 16 + lk) * P + p0 + lpb;
            #pragma unroll
            for (int u = 0; u < TM; ++u) ra[u] = ap[u];
            #pragma unroll
            for (int u = 0; u < TP; ++u) rb[u] = bp[u];
        }
        #pragma unroll
        for (int kk = 0; kk < 16; ++kk) {
            float av[TM], bv[TP];
            #pragma unroll
            for (int i = 0; i < TM; ++i) av[i] = As[kk][ty * TM + i];
            #pragma unroll
            for (int j = 0; j < TP; ++j) bv[j] = Bs[kk][tx * TP + j];
            #pragma unroll
            for (int i = 0; i < TM; ++i)
                #pragma unroll
                for (int j = 0; j < TP; ++j)
                    acc[i][j] += av[i] * bv[j];
        }
        __syncthreads();
    }

    #pragma unroll
    for (int i = 0; i < TM; ++i) {
        int m = m0 + ty * TM + i;
        float bb = bi ? ldin(bi, m, bf) : 0.f;
        #pragma unroll
        for (int j = 0; j < TP; ++j) {
            long idx = (long)m * c_ms + p0 + tx * TP + j;
            if (accum) atomicAdd(&C2[idx], acc[i][j]);
            else C2[idx] = acc[i][j] + bb;
        }
    }
}

// ---------------- GroupNorm (in place) + ReLU ----------------
__global__ __launch_bounds__(1024) void gn_relu_k(
    float* __restrict__ buf, const void* __restrict__ g, const void* __restrict__ bt,
    int C, int S, int groups, const int* __restrict__ flagp)
{
    int bf = *flagp;
    int nt = blockDim.x;
    int gid = blockIdx.x;
    int b = gid / groups, gr = gid % groups;
    int cpg = C / groups;
    long cnt = (long)cpg * S;
    float* base = buf + ((long)b * C + (long)gr * cpg) * S;
    double s = 0.0, s2 = 0.0;
    for (long i = threadIdx.x; i < cnt; i += nt) {
        float v = base[i];
        s += v; s2 += (double)v * v;
    }
    __shared__ double rs[1024], rq[1024];
    rs[threadIdx.x] = s; rq[threadIdx.x] = s2;
    __syncthreads();
    for (int off = nt >> 1; off > 0; off >>= 1) {
        if (threadIdx.x < off) { rs[threadIdx.x] += rs[threadIdx.x + off]; rq[threadIdx.x] += rq[threadIdx.x + off]; }
        __syncthreads();
    }
    double mean_d = rs[0] / (double)cnt;
    float mean = (float)mean_d;
    float var = (float)(rq[0] / (double)cnt - mean_d * mean_d);
    float rstd = rsqrtf(var + 1e-5f);
    for (long i = threadIdx.x; i < cnt; i += nt) {
        int c = gr * cpg + (int)(i / S);
        float v = (base[i] - mean) * rstd * ldin(g, c, bf) + ldin(bt, c, bf);
        base[i] = v > 0.f ? v : 0.f;
    }
}

// ---------------- sparse mask table ----------------
__global__ __launch_bounds__(384) void build_table_k(
    const void* __restrict__ mask, int* __restrict__ tabd,
    float* __restrict__ tabw, const int* __restrict__ flagp)
{
    int bf = *flagp;
    int nw = blockIdx.x;            // == w*32 + n (table base index)
    int w = nw >> 5, n = nw & 31;
    int tid = threadIdx.x;          // 0..383 ; d = tid-165 valid while d<=165
    int d = tid - 165;
    float v = 0.f;
    if (d <= 165) {
        if (d < 0) v = ldin(mask, (long)(254 + d) * 65536 + ((long)n * 256 + 254) * 8 + w, bf);
        else       v = ldin(mask, (long)(1 + d) * 65536 + ((long)n * 256 + 1) * 8 + w, bf);
    }
    __shared__ unsigned char nz[384];
    nz[tid] = (v != 0.f) ? 1 : 0;
    if (tid < 6) { tabd[nw * 6 + tid] = 0; tabw[nw * 6 + tid] = 0.f; }
    __syncthreads();
    if (v != 0.f) {
        int slot = 0;
        for (int j = 0; j < tid; ++j) slot += nz[j];
        if (slot < 6) { tabd[nw * 6 + slot] = d; tabw[nw * 6 + slot] = v; }
    }
}

__global__ void build_corr_k(const void* __restrict__ mask, const int* __restrict__ tabd,
                             const float* __restrict__ tabw, float* __restrict__ corrB,
                             const int* __restrict__ flagp) {
    int bf = *flagp;
    int idx = blockIdx.x * 256 + threadIdx.x;   // 65536
    if (idx >= 65536) return;
    int n = idx >> 11, p = idx & 2047;
    int t = p >> 3, w = p & 7;
    float mv = ldin(mask, ((long)n * 256 + t) * 8 + w, bf);
    float sub = 0.f;
    int base = (w * 32 + n) * 6;
    for (int k = 0; k < 6; ++k)
        if (tabd[base + k] == -t && tabw[base + k] != 0.f) sub += tabw[base + k];
    corrB[idx] = mv - sub;
}

// p0t[(b*32+n)*512 + h3] = P[b][h3][n][0]
__global__ void p0t_k(const float* __restrict__ P, float* __restrict__ p0t) {
    int idx = blockIdx.x * 256 + threadIdx.x;   // 32768
    if (idx >= 32768) return;
    int h3 = idx & 511, n = (idx >> 9) & 31, b = idx >> 14;
    p0t[idx] = P[(((long)(b * 512 + h3) * 32) + n) * 256];
}

// y[b][h3][t*8+w] = r3b[h3] + sum_{n,k} wt * P[b][h3][n][t+delta]
__global__ __launch_bounds__(256) void apply_y_k(
    const float* __restrict__ P, const int* __restrict__ tabd,
    const float* __restrict__ tabw, const void* __restrict__ r3b,
    float* __restrict__ y, const int* __restrict__ flagp)
{
    int bf = *flagp;
    int h3 = blockIdx.x;                 // 0..511
    __shared__ float Pl[2 * 8192];       // 64 KB: b=0 rows then b=1 rows
    __shared__ float4 Tp4[768];          // 12 KB packed (wt,d) pairs
    const float4* p04 = (const float4*)(P + (long)h3 * 8192);
    const float4* p14 = (const float4*)(P + (512L + h3) * 8192);
    float4* pl4 = (float4*)Pl;
    for (int i = threadIdx.x; i < 2048; i += 256) {
        pl4[i] = p04[i];
        pl4[i + 2048] = p14[i];
    }
    float2* tp2 = (float2*)Tp4;
    for (int i = threadIdx.x; i < 1536; i += 256)
        tp2[i] = make_float2(tabw[i], __int_as_float(tabd[i]));
    __syncthreads();

    int t = threadIdx.x;
    float a0[8], a1[8];
    #pragma unroll
    for (int w = 0; w < 8; ++w) { a0[w] = 0.f; a1[w] = 0.f; }

    #pragma unroll 1
    for (int n = 0; n < 32; ++n) {
        const float* Pn0 = Pl + (n << 8);
        #pragma unroll
        for (int w = 0; w < 8; ++w) {
            int e4 = ((w << 5) + n) * 3;     // 6 float2 = 3 float4
            float4 q0 = Tp4[e4], q1 = Tp4[e4 + 1], q2 = Tp4[e4 + 2];
            float wts[6] = {q0.x, q0.z, q1.x, q1.z, q2.x, q2.z};
            int   dss[6] = {__float_as_int(q0.y), __float_as_int(q0.w),
                            __float_as_int(q1.y), __float_as_int(q1.w),
                            __float_as_int(q2.y), __float_as_int(q2.w)};
            #pragma unroll
            for (int k = 0; k < 6; ++k) {
                int tau = t + dss[k];
                int idx = tau & 255;
                float wt = ((unsigned)tau < 256u) ? wts[k] : 0.f;
                a0[w] += wt * Pn0[idx];
                a1[w] += wt * Pn0[idx + 8192];
            }
        }
    }

    float bias = ldin(r3b, h3, bf);
    long y0 = (long)h3 * 2048 + (long)t * 8;
    long y1 = y0 + 512L * 2048;
    *(float4*)(y + y0)     = make_float4(a0[0] + bias, a0[1] + bias, a0[2] + bias, a0[3] + bias);
    *(float4*)(y + y0 + 4) = make_float4(a0[4] + bias, a0[5] + bias, a0[6] + bias, a0[7] + bias);
    *(float4*)(y + y1)     = make_float4(a1[0] + bias, a1[1] + bias, a1[2] + bias, a1[3] + bias);
    *(float4*)(y + y1 + 4) = make_float4(a1[4] + bias, a1[5] + bias, a1[6] + bias, a1[7] + bias);
}

// ---------------- bias pre-fills (for split-K atomic GEMMs) ----------------
__global__ void fill_bias_h_k(float* __restrict__ h0, const void* __restrict__ c1b,
                              const int* __restrict__ flagp) {
    int bf = *flagp;
    int idx = blockIdx.x * 256 + threadIdx.x;   // 131072
    if (idx >= 131072) return;
    int o = (idx >> 8) & 255;
    h0[idx] = ldin(c1b, o, bf);
}

__global__ void fill_bias_f_k(float* __restrict__ f, const void* __restrict__ r2b,
                              const int* __restrict__ flagp) {
    int bf = *flagp;
    int idx = blockIdx.x * 256 + threadIdx.x;
    if (idx >= 524288) return;
    int c = (idx >> 11) & 127;
    f[idx] = ldin(r2b, c, bf);
}

__global__ void fill_bias_heads_k(float* __restrict__ t1s, const void* __restrict__ s1b,
                                  const void* __restrict__ e1b, const int* __restrict__ flagp) {
    int bf = *flagp;
    int idx = blockIdx.x * 256 + threadIdx.x;   // 1048576
    if (idx >= 1048576) return;
    int region = idx >> 18;                     // 0,1 -> t1s ; 2,3 -> t1e
    int c = (idx >> 11) & 127;
    t1s[idx] = (region < 2) ? ldin(s1b, c, bf) : ldin(e1b, c, bf);
}

__global__ void head_out_k(const float* __restrict__ t1s, const float* __restrict__ t1e,
                           const void* __restrict__ s2w, const void* __restrict__ s2b,
                           const void* __restrict__ e2w, const void* __restrict__ e2b,
                           void* __restrict__ out, const int* __restrict__ flagp) {
    int bf = *flagp;
    int idx = blockIdx.x * 256 + threadIdx.x;   // 4096
    if (idx >= 4096) return;
    int b = idx >> 11, p = idx & 2047;
    const float* ts = t1s + (long)b * 262144 + p;
    const float* te = t1e + (long)b * 262144 + p;
    float as = ldin(s2b, 0, bf), ae = ldin(e2b, 0, bf);
    #pragma unroll 8
    for (int c = 0; c < 128; ++c) {
        as += ldin(s2w, c, bf) * ts[(long)c * 2048];
        ae += ldin(e2w, c, bf) * te[(long)c * 2048];
    }
    float vs = 1.f / (1.f + expf(-as));
    float ve = 1.f / (1.f + expf(-ae));
    long o0 = ((long)b * 2) * 2048 + p;
    long o1 = ((long)b * 2 + 1) * 2048 + p;
    if (bf) {
        ((bf16*)out)[o0] = __float2bfloat16(vs);
        ((bf16*)out)[o1] = __float2bfloat16(ve);
    } else {
        ((float*)out)[o0] = vs;
        ((float*)out)[o1] = ve;
    }
}

// ---------------- launch ----------------
extern "C" void kernel_launch(void* const* d_in, const int* in_sizes, int n_in,
                              void* d_out, int out_size, void* d_ws, size_t ws_size,
                              hipStream_t stream) {
    const void* x    = d_in[0];
    const void* mask = d_in[1];
    const void* c1w  = d_in[2];
    const void* c1b  = d_in[3];
    const void* gn1g = d_in[4];
    const void* gn1b = d_in[5];
    const void* w3   = d_in[6];
    const void* r3b  = d_in[7];
    const void* gn3g = d_in[8];
    const void* gn3b = d_in[9];
    const void* w2   = d_in[10];
    const void* r2b  = d_in[11];
    const void* gn2g = d_in[12];
    const void* gn2b = d_in[13];
    const void* s1w  = d_in[14];
    const void* s1b  = d_in[15];
    const void* sgng = d_in[16];
    const void* sgnb = d_in[17];
    const void* s2w  = d_in[18];
    const void* s2b  = d_in[19];
    const void* e1w  = d_in[20];
    const void* e1b  = d_in[21];
    const void* egng = d_in[22];
    const void* egnb = d_in[23];
    const void* e2w  = d_in[24];
    const void* e2b  = d_in[25];
    float* ws = (float*)d_ws;

    // layout (floats); Pb region reused for colx (before) and col (after)
    int*   flagI = (int*)(ws + 0);       // 64 reserved
    float* h     = ws + 64;              // 131072
    float* c1t   = ws + 131136;          // 393216
    float* w2t   = ws + 524352;          // 65536
    float* s1t   = ws + 589888;          // 147456
    float* e1t   = ws + 737344;          // 147456 (adjacent to s1t)
    float* corrB = ws + 884800;          // 65536
    float* tabw  = ws + 950336;          // 1536
    int*   tabd  = (int*)(ws + 951872);  // 1536
    float* p0t   = ws + 953408;          // 32768
    float* t1s   = ws + 986176;          // 524288
    float* t1e   = ws + 1510464;         // 524288 (adjacent to t1s)
    float* f     = ws + 2034752;         // 524288
    float* y     = ws + 2559040;         // 2097152
    float* w3t   = ws + 4656192;         // 4194304
    float* Pb    = ws + 8850496;         // 8388608  (total ~69 MB)
    float* colx  = Pb;                   // alias: dead before Pb written
    float* col   = Pb;                   // alias: Pb dead before col written

    dim3 blk(256);
    dim3 blkG(1024);

    detect_k<<<dim3(1), blk, 0, stream>>>((const unsigned short*)x, flagI);

    // weight transposes + table extraction
    transpose_w_k<<<dim3(1536), blk, 0, stream>>>(c1w, c1t, 256, 1536, flagI);
    transpose_w_k<<<dim3(256),  blk, 0, stream>>>(w2,  w2t, 128, 512, flagI);
    transpose_w_k<<<dim3(576),  blk, 0, stream>>>(s1w, s1t, 128, 1152, flagI);
    transpose_w_k<<<dim3(576),  blk, 0, stream>>>(e1w, e1t, 128, 1152, flagI);
    transpose_w3_k<<<dim3(2048), blk, 0, stream>>>(w3, w3t, flagI);
    build_table_k<<<dim3(256), dim3(384), 0, stream>>>(mask, tabd, tabw, flagI);
    build_corr_k<<<dim3(256), blk, 0, stream>>>(mask, tabd, tabw, corrB, flagI);

    // conv1 (im2col + split-K GEMM) + GN1 + ReLU
    im2col_x_k<<<dim3(3072), blk, 0, stream>>>(x, colx, flagI);
    fill_bias_h_k<<<dim3(512), blk, 0, stream>>>(h, c1b, flagI);
    gemm_t<64,64,4,4><<<dim3(4,4,16), blk, 0, stream>>>(
        c1t, colx, h, nullptr, nullptr, 256, 1536, 256,
        1, 1, 0L, 393216L, 65536L, 0L, 256, 2, 8, 1, flagI);
    gn_relu_k<<<dim3(64), blkG, 0, stream>>>(h, gn1g, gn1b, 256, 256, 32, flagI);

    // P[b,h3,n,tau] = sum_c w3[h3,c,n] h[b,c,tau]  (128x128 tile, 8x8/thread)
    gemm_t<128,128,8,8><<<dim3(2,4,64), blk, 0, stream>>>(
        w3t, h, Pb, nullptr, nullptr, 512, 256, 256,
        32, 32, 131072L, 65536L, 4194304L, 256L, 8192, 64, 1, 0, flagI);

    // sparse mask apply + bin-0 correction + GN3 + ReLU
    apply_y_k<<<dim3(512), blk, 0, stream>>>(Pb, tabd, tabw, r3b, y, flagI);
    p0t_k<<<dim3(128), blk, 0, stream>>>(Pb, p0t);
    gemm_t<64,64,4,4><<<dim3(32,8,2), blk, 0, stream>>>(
        p0t, corrB, y, nullptr, nullptr, 512, 32, 2048,
        2, 1, 16384L, 0L, 0L, 1048576L, 2048, 2, 1, 1, flagI);
    gn_relu_k<<<dim3(64), blkG, 0, stream>>>(y, gn3g, gn3b, 512, 2048, 32, flagI);

    // r2d 1x1 (split-K x4, bias pre-filled) + GN2 + ReLU
    fill_bias_f_k<<<dim3(2048), blk, 0, stream>>>(f, r2b, flagI);
    gemm_t<64,64,4,4><<<dim3(32,2,8), blk, 0, stream>>>(
        w2t, y, f, nullptr, nullptr, 128, 512, 2048,
        1, 1, 0L, 1048576L, 262144L, 0L, 2048, 2, 4, 1, flagI);
    gn_relu_k<<<dim3(64), blkG, 0, stream>>>(f, gn2g, gn2b, 128, 2048, 32, flagI);

    // both heads: shared im2col + split-K 128x128 GEMM (bias pre-filled) + GN + ReLU
    im2col_f_k<<<dim3(18432), blk, 0, stream>>>(f, col);
    fill_bias_heads_k<<<dim3(4096), blk, 0, stream>>>(t1s, s1b, e1b, flagI);
    gemm_t<128,128,8,8><<<dim3(16,1,16), blk, 0, stream>>>(
        s1t, col, t1s, nullptr, nullptr, 128, 1152, 2048,
        2, 2, 147456L, 2359296L, 262144L, 524288L, 2048, 4, 4, 1, flagI);
    gn_relu_k<<<dim3(64), blkG, 0, stream>>>(t1s, sgng, sgnb, 128, 2048, 32, flagI);
    gn_relu_k<<<dim3(64), blkG, 0, stream>>>(t1e, egng, egnb, 128, 2048, 32, flagI);

    // 1x1 head convs + sigmoid -> output
    head_out_k<<<dim3(16), blk, 0, stream>>>(t1s, t1e, s2w, s2b, e2w, e2b, d_out, flagI);
}

// Round 8
// 597.998 us; speedup vs baseline: 1.0333x; 1.0333x over previous
//
#include <hip/hip_runtime.h>
#include <hip/hip_bf16.h>

typedef __hip_bfloat16 bf16;

static __device__ __forceinline__ float b2f(bf16 v) { return __bfloat162float(v); }

// flag-aware input load: bf==1 -> bf16, bf==0 -> f32
static __device__ __forceinline__ float ldin(const void* p, long i, int bf) {
    return bf ? b2f(((const bf16*)p)[i]) : ((const float*)p)[i];
}

// ---------------- dtype detect ----------------
__global__ void detect_k(const unsigned short* __restrict__ x16, int* __restrict__ flag) {
    __shared__ int cnt[256];
    unsigned short u = x16[threadIdx.x];
    int e = (u >> 7) & 0xFF;
    cnt[threadIdx.x] = (e >= 100 && e <= 140) ? 1 : 0;
    __syncthreads();
    for (int off = 128; off > 0; off >>= 1) {
        if (threadIdx.x < off) cnt[threadIdx.x] += cnt[threadIdx.x + off];
        __syncthreads();
    }
    if (threadIdx.x == 0) *flag = (cnt[0] > 217) ? 1 : 0;
}

// ---------------- transposes ----------------
__global__ void transpose_w_k(const void* __restrict__ in, float* __restrict__ out,
                              int M, int K, const int* __restrict__ flagp) {
    int bf = *flagp;
    int idx = blockIdx.x * 256 + threadIdx.x;
    if (idx >= M * K) return;
    int k = idx / M, m = idx - k * M;
    out[idx] = ldin(in, (long)m * K + k, bf);
}

// out[(n*256 + c)*512 + h3] = w3[(h3*256 + c)*32 + n]
__global__ void transpose_w3_k(const void* __restrict__ w3, float* __restrict__ out,
                               const int* __restrict__ flagp) {
    int bf = *flagp;
    int bid = blockIdx.x;            // 2048 = 8 h3-tiles * 256 c
    int h30 = (bid & 7) * 64;
    int c = bid >> 3;
    __shared__ float tile[64][33];
    int tid = threadIdx.x;
    for (int i = tid; i < 64 * 32; i += 256) {
        int hl = i >> 5, n = i & 31;
        tile[hl][n] = ldin(w3, ((long)(h30 + hl) * 256 + c) * 32 + n, bf);
    }
    __syncthreads();
    for (int i = tid; i < 64 * 32; i += 256) {
        int n = i >> 6, hl = i & 63;
        out[((long)n * 256 + c) * 512 + h30 + hl] = tile[hl][n];
    }
}

// ---------------- im2col ----------------
__global__ void im2col_x_k(const void* __restrict__ x, float* __restrict__ colx,
                           const int* __restrict__ flagp) {
    int bf = *flagp;
    int idx = blockIdx.x * 256 + threadIdx.x;   // 786432
    if (idx >= 786432) return;
    int t = idx & 255;
    int b = idx / 393216;
    int k = (idx - b * 393216) >> 8;
    int c = k / 3, q = k - c * 3;
    int tt = t + q - 1;
    colx[idx] = (tt >= 0 && tt < 256) ? ldin(x, ((long)b * 512 + c) * 256 + tt, bf) : 0.f;
}

__global__ void im2col_f_k(const float* __restrict__ f, float* __restrict__ col) {
    int idx = blockIdx.x * 256 + threadIdx.x;   // 4718592
    if (idx >= 4718592) return;
    int p = idx & 2047;
    int rem = idx >> 11;
    int b = rem / 1152;
    int k = rem - b * 1152;
    int c = k / 9, q = k - c * 9;
    int dy = q / 3, dx = q - dy * 3;
    int t = p >> 3, w = p & 7;
    int tt = t + dy - 1, ww = w + dx - 1;
    col[idx] = (tt >= 0 && tt < 256 && ww >= 0 && ww < 8)
                   ? f[((long)b * 128 + c) * 2048 + tt * 8 + ww] : 0.f;
}

// ---------------- generic tiled GEMM w/ register prefetch (64x64, 4x4) ----------------
template<int BM, int BP, int TM, int TP>
__global__ __launch_bounds__(256) void gemm_t(
    const float* __restrict__ A, const float* __restrict__ B, float* __restrict__ C,
    const void* __restrict__ bias, const void* __restrict__ bias2,
    int M, int K, int P, int az_mod, int bz_div,
    long a_zs, long b_zs, long c_zs1, long c_zs2, int c_ms,
    int zmod, int ksplit, int accum, const int* __restrict__ flagp)
{
    int bf = *flagp;
    int zraw = blockIdx.z;
    int z = zraw % zmod;
    int ks = zraw / zmod;
    int klen = K / ksplit;
    int kbeg = ks * klen;
    int kend = kbeg + klen;
    int za = z % az_mod;
    const float* A2 = A + (long)za * a_zs;
    const float* B2 = B + (long)(z / bz_div) * b_zs;
    float* C2 = C + (long)(z / bz_div) * c_zs1 + (long)za * c_zs2;
    const void* bi = (bias2 != nullptr && za != 0) ? bias2 : bias;

    __shared__ float As[16][BM];
    __shared__ float Bs[16][BP];
    int tid = threadIdx.x;
    int ty = tid >> 4, tx = tid & 15;
    int lk = tid >> 4;
    int lma = (tid & 15) * TM;
    int lpb = (tid & 15) * TP;
    int m0 = blockIdx.y * BM, p0 = blockIdx.x * BP;

    float acc[TM][TP];
    #pragma unroll
    for (int i = 0; i < TM; ++i)
        #pragma unroll
        for (int j = 0; j < TP; ++j) acc[i][j] = 0.f;

    float ra[TM], rb[TP];
    {
        const float* ap = A2 + (long)(kbeg + lk) * M + m0 + lma;
        const float* bp = B2 + (long)(kbeg + lk) * P + p0 + lpb;
        #pragma unroll
        for (int u = 0; u < TM; ++u) ra[u] = ap[u];
        #pragma unroll
        for (int u = 0; u < TP; ++u) rb[u] = bp[u];
    }

    for (int kc = kbeg; kc < kend; kc += 16) {
        #pragma unroll
        for (int u = 0; u < TM; ++u) As[lk][lma + u] = ra[u];
        #pragma unroll
        for (int u = 0; u < TP; ++u) Bs[lk][lpb + u] = rb[u];
        __syncthreads();
        if (kc + 16 < kend) {
            const float* ap = A2 + (long)(kc + 16 + lk) * M + m0 + lma;
            const float* bp = B2 + (long)(kc + 16 + lk) * P + p0 + lpb;
            #pragma unroll
            for (int u = 0; u < TM; ++u) ra[u] = ap[u];
            #pragma unroll
            for (int u = 0; u < TP; ++u) rb[u] = bp[u];
        }
        #pragma unroll
        for (int kk = 0; kk < 16; ++kk) {
            float av[TM], bv[TP];
            #pragma unroll
            for (int i = 0; i < TM; ++i) av[i] = As[kk][ty * TM + i];
            #pragma unroll
            for (int j = 0; j < TP; ++j) bv[j] = Bs[kk][tx * TP + j];
            #pragma unroll
            for (int i = 0; i < TM; ++i)
                #pragma unroll
                for (int j = 0; j < TP; ++j)
                    acc[i][j] += av[i] * bv[j];
        }
        __syncthreads();
    }

    #pragma unroll
    for (int i = 0; i < TM; ++i) {
        int m = m0 + ty * TM + i;
        float bb = bi ? ldin(bi, m, bf) : 0.f;
        #pragma unroll
        for (int j = 0; j < TP; ++j) {
            long idx = (long)m * c_ms + p0 + tx * TP + j;
            if (accum) atomicAdd(&C2[idx], acc[i][j]);
            else C2[idx] = acc[i][j] + bb;
        }
    }
}

// ---------------- 128x128 quad GEMM: 8x8/thread as 2x2 quadrants of 4x4 ----------------
// All LDS access is stride-4-float b128 (2-way bank aliasing = free); no conflicts.
__global__ __launch_bounds__(256) void gemm_q(
    const float* __restrict__ A, const float* __restrict__ B, float* __restrict__ C,
    const void* __restrict__ bias, const void* __restrict__ bias2,
    int M, int K, int P, int az_mod, int bz_div,
    long a_zs, long b_zs, long c_zs1, long c_zs2, int c_ms,
    int zmod, int ksplit, int accum, const int* __restrict__ flagp)
{
    int bf = *flagp;
    int zraw = blockIdx.z;
    int z = zraw % zmod;
    int ks = zraw / zmod;
    int klen = K / ksplit;
    int kbeg = ks * klen, kend = kbeg + klen;
    int za = z % az_mod;
    const float* A2 = A + (long)za * a_zs;
    const float* B2 = B + (long)(z / bz_div) * b_zs;
    float* C2 = C + (long)(z / bz_div) * c_zs1 + (long)za * c_zs2;
    const void* bi = (bias2 != nullptr && za != 0) ? bias2 : bias;

    __shared__ float As[16][128];
    __shared__ float Bs[16][128];
    int tid = threadIdx.x;
    int ty = tid >> 4, tx = tid & 15;   // 16x16 thread grid
    int lk = tid >> 4;
    int lc4 = (tid & 15) * 4;
    int m0 = blockIdx.y * 128, p0 = blockIdx.x * 128;

    float acc[8][8];
    #pragma unroll
    for (int i = 0; i < 8; ++i)
        #pragma unroll
        for (int j = 0; j < 8; ++j) acc[i][j] = 0.f;

    float4 ra0, ra1, rb0, rb1;
    {
        const float* ap = A2 + (long)(kbeg + lk) * M + m0 + lc4;
        const float* bp = B2 + (long)(kbeg + lk) * P + p0 + lc4;
        ra0 = *(const float4*)ap;  ra1 = *(const float4*)(ap + 64);
        rb0 = *(const float4*)bp;  rb1 = *(const float4*)(bp + 64);
    }

    for (int kc = kbeg; kc < kend; kc += 16) {
        *(float4*)&As[lk][lc4]      = ra0;
        *(float4*)&As[lk][64 + lc4] = ra1;
        *(float4*)&Bs[lk][lc4]      = rb0;
        *(float4*)&Bs[lk][64 + lc4] = rb1;
        __syncthreads();
        if (kc + 16 < kend) {
            const float* ap = A2 + (long)(kc + 16 + lk) * M + m0 + lc4;
            const float* bp = B2 + (long)(kc + 16 + lk) * P + p0 + lc4;
            ra0 = *(const float4*)ap;  ra1 = *(const float4*)(ap + 64);
            rb0 = *(const float4*)bp;  rb1 = *(const float4*)(bp + 64);
        }
        #pragma unroll
        for (int kk = 0; kk < 16; ++kk) {
            float4 av0 = *(float4*)&As[kk][ty * 4];
            float4 av1 = *(float4*)&As[kk][64 + ty * 4];
            float4 bv0 = *(float4*)&Bs[kk][tx * 4];
            float4 bv1 = *(float4*)&Bs[kk][64 + tx * 4];
            float av[8] = {av0.x, av0.y, av0.z, av0.w, av1.x, av1.y, av1.z, av1.w};
            float bv[8] = {bv0.x, bv0.y, bv0.z, bv0.w, bv1.x, bv1.y, bv1.z, bv1.w};
            #pragma unroll
            for (int i = 0; i < 8; ++i)
                #pragma unroll
                for (int j = 0; j < 8; ++j)
                    acc[i][j] += av[i] * bv[j];
        }
        __syncthreads();
    }

    #pragma unroll
    for (int r = 0; r < 2; ++r)
        #pragma unroll
        for (int i = 0; i < 4; ++i) {
            int m = m0 + r * 64 + ty * 4 + i;
            float bb = bi ? ldin(bi, m, bf) : 0.f;
            #pragma unroll
            for (int c = 0; c < 2; ++c)
                #pragma unroll
                for (int j = 0; j < 4; ++j) {
                    long idx = (long)m * c_ms + p0 + c * 64 + tx * 4 + j;
                    if (accum) atomicAdd(&C2[idx], acc[r * 4 + i][c * 4 + j]);
                    else C2[idx] = acc[r * 4 + i][c * 4 + j] + bb;
                }
        }
}

// ---------------- GroupNorm (in place) + ReLU ----------------
__global__ __launch_bounds__(1024) void gn_relu_k(
    float* __restrict__ buf, const void* __restrict__ g, const void* __restrict__ bt,
    int C, int S, int groups, const int* __restrict__ flagp)
{
    int bf = *flagp;
    int nt = blockDim.x;
    int gid = blockIdx.x;
    int b = gid / groups, gr = gid % groups;
    int cpg = C / groups;
    long cnt = (long)cpg * S;
    float* base = buf + ((long)b * C + (long)gr * cpg) * S;
    double s = 0.0, s2 = 0.0;
    for (long i = threadIdx.x; i < cnt; i += nt) {
        float v = base[i];
        s += v; s2 += (double)v * v;
    }
    __shared__ double rs[1024], rq[1024];
    rs[threadIdx.x] = s; rq[threadIdx.x] = s2;
    __syncthreads();
    for (int off = nt >> 1; off > 0; off >>= 1) {
        if (threadIdx.x < off) { rs[threadIdx.x] += rs[threadIdx.x + off]; rq[threadIdx.x] += rq[threadIdx.x + off]; }
        __syncthreads();
    }
    double mean_d = rs[0] / (double)cnt;
    float mean = (float)mean_d;
    float var = (float)(rq[0] / (double)cnt - mean_d * mean_d);
    float rstd = rsqrtf(var + 1e-5f);
    for (long i = threadIdx.x; i < cnt; i += nt) {
        int c = gr * cpg + (int)(i / S);
        float v = (base[i] - mean) * rstd * ldin(g, c, bf) + ldin(bt, c, bf);
        base[i] = v > 0.f ? v : 0.f;
    }
}

// ---------------- sparse mask table ----------------
__global__ __launch_bounds__(384) void build_table_k(
    const void* __restrict__ mask, int* __restrict__ tabd,
    float* __restrict__ tabw, const int* __restrict__ flagp)
{
    int bf = *flagp;
    int nw = blockIdx.x;            // == w*32 + n (table base index)
    int w = nw >> 5, n = nw & 31;
    int tid = threadIdx.x;          // 0..383 ; d = tid-165 valid while d<=165
    int d = tid - 165;
    float v = 0.f;
    if (d <= 165) {
        if (d < 0) v = ldin(mask, (long)(254 + d) * 65536 + ((long)n * 256 + 254) * 8 + w, bf);
        else       v = ldin(mask, (long)(1 + d) * 65536 + ((long)n * 256 + 1) * 8 + w, bf);
    }
    __shared__ unsigned char nz[384];
    nz[tid] = (v != 0.f) ? 1 : 0;
    if (tid < 6) { tabd[nw * 6 + tid] = 0; tabw[nw * 6 + tid] = 0.f; }
    __syncthreads();
    if (v != 0.f) {
        int slot = 0;
        for (int j = 0; j < tid; ++j) slot += nz[j];
        if (slot < 6) { tabd[nw * 6 + slot] = d; tabw[nw * 6 + slot] = v; }
    }
}

__global__ void build_corr_k(const void* __restrict__ mask, const int* __restrict__ tabd,
                             const float* __restrict__ tabw, float* __restrict__ corrB,
                             const int* __restrict__ flagp) {
    int bf = *flagp;
    int idx = blockIdx.x * 256 + threadIdx.x;   // 65536
    if (idx >= 65536) return;
    int n = idx >> 11, p = idx & 2047;
    int t = p >> 3, w = p & 7;
    float mv = ldin(mask, ((long)n * 256 + t) * 8 + w, bf);
    float sub = 0.f;
    int base = (w * 32 + n) * 6;
    for (int k = 0; k < 6; ++k)
        if (tabd[base + k] == -t && tabw[base + k] != 0.f) sub += tabw[base + k];
    corrB[idx] = mv - sub;
}

// p0t[(b*32+n)*512 + h3] = P[b][h3][n][0]
__global__ void p0t_k(const float* __restrict__ P, float* __restrict__ p0t) {
    int idx = blockIdx.x * 256 + threadIdx.x;   // 32768
    if (idx >= 32768) return;
    int h3 = idx & 511, n = (idx >> 9) & 31, b = idx >> 14;
    p0t[idx] = P[(((long)(b * 512 + h3) * 32) + n) * 256];
}

// y[b][h3][t*8+w] = r3b[h3] + sum_{n,k} wt * P[b][h3][n][t+delta]
__global__ __launch_bounds__(256) void apply_y_k(
    const float* __restrict__ P, const int* __restrict__ tabd,
    const float* __restrict__ tabw, const void* __restrict__ r3b,
    float* __restrict__ y, const int* __restrict__ flagp)
{
    int bf = *flagp;
    int h3 = blockIdx.x;                 // 0..511
    __shared__ float Pl[2 * 8192];       // 64 KB: b=0 rows then b=1 rows
    __shared__ float4 Tp4[768];          // 12 KB packed (wt,d) pairs
    const float4* p04 = (const float4*)(P + (long)h3 * 8192);
    const float4* p14 = (const float4*)(P + (512L + h3) * 8192);
    float4* pl4 = (float4*)Pl;
    for (int i = threadIdx.x; i < 2048; i += 256) {
        pl4[i] = p04[i];
        pl4[i + 2048] = p14[i];
    }
    float2* tp2 = (float2*)Tp4;
    for (int i = threadIdx.x; i < 1536; i += 256)
        tp2[i] = make_float2(tabw[i], __int_as_float(tabd[i]));
    __syncthreads();

    int t = threadIdx.x;
    float a0[8], a1[8];
    #pragma unroll
    for (int w = 0; w < 8; ++w) { a0[w] = 0.f; a1[w] = 0.f; }

    #pragma unroll 1
    for (int n = 0; n < 32; ++n) {
        const float* Pn0 = Pl + (n << 8);
        #pragma unroll
        for (int w = 0; w < 8; ++w) {
            int e4 = ((w << 5) + n) * 3;     // 6 float2 = 3 float4
            float4 q0 = Tp4[e4], q1 = Tp4[e4 + 1], q2 = Tp4[e4 + 2];
            float wts[6] = {q0.x, q0.z, q1.x, q1.z, q2.x, q2.z};
            int   dss[6] = {__float_as_int(q0.y), __float_as_int(q0.w),
                            __float_as_int(q1.y), __float_as_int(q1.w),
                            __float_as_int(q2.y), __float_as_int(q2.w)};
            #pragma unroll
            for (int k = 0; k < 6; ++k) {
                int tau = t + dss[k];
                int idx = tau & 255;
                float wt = ((unsigned)tau < 256u) ? wts[k] : 0.f;
                a0[w] += wt * Pn0[idx];
                a1[w] += wt * Pn0[idx + 8192];
            }
        }
    }

    float bias = ldin(r3b, h3, bf);
    long y0 = (long)h3 * 2048 + (long)t * 8;
    long y1 = y0 + 512L * 2048;
    *(float4*)(y + y0)     = make_float4(a0[0] + bias, a0[1] + bias, a0[2] + bias, a0[3] + bias);
    *(float4*)(y + y0 + 4) = make_float4(a0[4] + bias, a0[5] + bias, a0[6] + bias, a0[7] + bias);
    *(float4*)(y + y1)     = make_float4(a1[0] + bias, a1[1] + bias, a1[2] + bias, a1[3] + bias);
    *(float4*)(y + y1 + 4) = make_float4(a1[4] + bias, a1[5] + bias, a1[6] + bias, a1[7] + bias);
}

// ---------------- bias pre-fills (for split-K atomic GEMMs) ----------------
__global__ void fill_bias_h_k(float* __restrict__ h0, const void* __restrict__ c1b,
                              const int* __restrict__ flagp) {
    int bf = *flagp;
    int idx = blockIdx.x * 256 + threadIdx.x;   // 131072
    if (idx >= 131072) return;
    int o = (idx >> 8) & 255;
    h0[idx] = ldin(c1b, o, bf);
}

__global__ void fill_bias_f_k(float* __restrict__ f, const void* __restrict__ r2b,
                              const int* __restrict__ flagp) {
    int bf = *flagp;
    int idx = blockIdx.x * 256 + threadIdx.x;
    if (idx >= 524288) return;
    int c = (idx >> 11) & 127;
    f[idx] = ldin(r2b, c, bf);
}

__global__ void fill_bias_heads_k(float* __restrict__ t1s, const void* __restrict__ s1b,
                                  const void* __restrict__ e1b, const int* __restrict__ flagp) {
    int bf = *flagp;
    int idx = blockIdx.x * 256 + threadIdx.x;   // 1048576
    if (idx >= 1048576) return;
    int region = idx >> 18;                     // 0,1 -> t1s ; 2,3 -> t1e
    int c = (idx >> 11) & 127;
    t1s[idx] = (region < 2) ? ldin(s1b, c, bf) : ldin(e1b, c, bf);
}

__global__ void head_out_k(const float* __restrict__ t1s, const float* __restrict__ t1e,
                           const void* __restrict__ s2w, const void* __restrict__ s2b,
                           const void* __restrict__ e2w, const void* __restrict__ e2b,
                           void* __restrict__ out, const int* __restrict__ flagp) {
    int bf = *flagp;
    int idx = blockIdx.x * 256 + threadIdx.x;   // 4096
    if (idx >= 4096) return;
    int b = idx >> 11, p = idx & 2047;
    const float* ts = t1s + (long)b * 262144 + p;
    const float* te = t1e + (long)b * 262144 + p;
    float as = ldin(s2b, 0, bf), ae = ldin(e2b, 0, bf);
    #pragma unroll 8
    for (int c = 0; c < 128; ++c) {
        as += ldin(s2w, c, bf) * ts[(long)c * 2048];
        ae += ldin(e2w, c, bf) * te[(long)c * 2048];
    }
    float vs = 1.f / (1.f + expf(-as));
    float ve = 1.f / (1.f + expf(-ae));
    long o0 = ((long)b * 2) * 2048 + p;
    long o1 = ((long)b * 2 + 1) * 2048 + p;
    if (bf) {
        ((bf16*)out)[o0] = __float2bfloat16(vs);
        ((bf16*)out)[o1] = __float2bfloat16(ve);
    } else {
        ((float*)out)[o0] = vs;
        ((float*)out)[o1] = ve;
    }
}

// ---------------- launch ----------------
extern "C" void kernel_launch(void* const* d_in, const int* in_sizes, int n_in,
                              void* d_out, int out_size, void* d_ws, size_t ws_size,
                              hipStream_t stream) {
    const void* x    = d_in[0];
    const void* mask = d_in[1];
    const void* c1w  = d_in[2];
    const void* c1b  = d_in[3];
    const void* gn1g = d_in[4];
    const void* gn1b = d_in[5];
    const void* w3   = d_in[6];
    const void* r3b  = d_in[7];
    const void* gn3g = d_in[8];
    const void* gn3b = d_in[9];
    const void* w2   = d_in[10];
    const void* r2b  = d_in[11];
    const void* gn2g = d_in[12];
    const void* gn2b = d_in[13];
    const void* s1w  = d_in[14];
    const void* s1b  = d_in[15];
    const void* sgng = d_in[16];
    const void* sgnb = d_in[17];
    const void* s2w  = d_in[18];
    const void* s2b  = d_in[19];
    const void* e1w  = d_in[20];
    const void* e1b  = d_in[21];
    const void* egng = d_in[22];
    const void* egnb = d_in[23];
    const void* e2w  = d_in[24];
    const void* e2b  = d_in[25];
    float* ws = (float*)d_ws;

    // layout (floats); Pb region reused for colx (before) and col (after)
    int*   flagI = (int*)(ws + 0);       // 64 reserved
    float* h     = ws + 64;              // 131072
    float* c1t   = ws + 131136;          // 393216
    float* w2t   = ws + 524352;          // 65536
    float* s1t   = ws + 589888;          // 147456
    float* e1t   = ws + 737344;          // 147456 (adjacent to s1t)
    float* corrB = ws + 884800;          // 65536
    float* tabw  = ws + 950336;          // 1536
    int*   tabd  = (int*)(ws + 951872);  // 1536
    float* p0t   = ws + 953408;          // 32768
    float* t1s   = ws + 986176;          // 524288
    float* t1e   = ws + 1510464;         // 524288 (adjacent to t1s)
    float* f     = ws + 2034752;         // 524288
    float* y     = ws + 2559040;         // 2097152
    float* w3t   = ws + 4656192;         // 4194304
    float* Pb    = ws + 8850496;         // 8388608  (total ~69 MB)
    float* colx  = Pb;                   // alias: dead before Pb written
    float* col   = Pb;                   // alias: Pb dead before col written

    dim3 blk(256);
    dim3 blkG(1024);

    detect_k<<<dim3(1), blk, 0, stream>>>((const unsigned short*)x, flagI);

    // weight transposes + table extraction
    transpose_w_k<<<dim3(1536), blk, 0, stream>>>(c1w, c1t, 256, 1536, flagI);
    transpose_w_k<<<dim3(256),  blk, 0, stream>>>(w2,  w2t, 128, 512, flagI);
    transpose_w_k<<<dim3(576),  blk, 0, stream>>>(s1w, s1t, 128, 1152, flagI);
    transpose_w_k<<<dim3(576),  blk, 0, stream>>>(e1w, e1t, 128, 1152, flagI);
    transpose_w3_k<<<dim3(2048), blk, 0, stream>>>(w3, w3t, flagI);
    build_table_k<<<dim3(256), dim3(384), 0, stream>>>(mask, tabd, tabw, flagI);
    build_corr_k<<<dim3(256), blk, 0, stream>>>(mask, tabd, tabw, corrB, flagI);

    // conv1 (im2col + split-K GEMM) + GN1 + ReLU
    im2col_x_k<<<dim3(3072), blk, 0, stream>>>(x, colx, flagI);
    fill_bias_h_k<<<dim3(512), blk, 0, stream>>>(h, c1b, flagI);
    gemm_t<64,64,4,4><<<dim3(4,4,16), blk, 0, stream>>>(
        c1t, colx, h, nullptr, nullptr, 256, 1536, 256,
        1, 1, 0L, 393216L, 65536L, 0L, 256, 2, 8, 1, flagI);
    gn_relu_k<<<dim3(64), blkG, 0, stream>>>(h, gn1g, gn1b, 256, 256, 32, flagI);

    // P[b,h3,n,tau] = sum_c w3[h3,c,n] h[b,c,tau]  (128x128 quad tile, 512 blocks)
    gemm_q<<<dim3(2,4,64), blk, 0, stream>>>(
        w3t, h, Pb, nullptr, nullptr, 512, 256, 256,
        32, 32, 131072L, 65536L, 4194304L, 256L, 8192, 64, 1, 0, flagI);

    // sparse mask apply + bin-0 correction + GN3 + ReLU
    apply_y_k<<<dim3(512), blk, 0, stream>>>(Pb, tabd, tabw, r3b, y, flagI);
    p0t_k<<<dim3(128), blk, 0, stream>>>(Pb, p0t);
    gemm_t<64,64,4,4><<<dim3(32,8,2), blk, 0, stream>>>(
        p0t, corrB, y, nullptr, nullptr, 512, 32, 2048,
        2, 1, 16384L, 0L, 0L, 1048576L, 2048, 2, 1, 1, flagI);
    gn_relu_k<<<dim3(64), blkG, 0, stream>>>(y, gn3g, gn3b, 512, 2048, 32, flagI);

    // r2d 1x1 (split-K x4, bias pre-filled) + GN2 + ReLU
    fill_bias_f_k<<<dim3(2048), blk, 0, stream>>>(f, r2b, flagI);
    gemm_t<64,64,4,4><<<dim3(32,2,8), blk, 0, stream>>>(
        w2t, y, f, nullptr, nullptr, 128, 512, 2048,
        1, 1, 0L, 1048576L, 262144L, 0L, 2048, 2, 4, 1, flagI);
    gn_relu_k<<<dim3(64), blkG, 0, stream>>>(f, gn2g, gn2b, 128, 2048, 32, flagI);

    // both heads: shared im2col + split-K quad GEMM (bias pre-filled) + GN + ReLU
    im2col_f_k<<<dim3(18432), blk, 0, stream>>>(f, col);
    fill_bias_heads_k<<<dim3(4096), blk, 0, stream>>>(t1s, s1b, e1b, flagI);
    gemm_q<<<dim3(16,1,32), blk, 0, stream>>>(
        s1t, col, t1s, nullptr, nullptr, 128, 1152, 2048,
        2, 2, 147456L, 2359296L, 262144L, 524288L, 2048, 4, 8, 1, flagI);
    gn_relu_k<<<dim3(64), blkG, 0, stream>>>(t1s, sgng, sgnb, 128, 2048, 32, flagI);
    gn_relu_k<<<dim3(64), blkG, 0, stream>>>(t1e, egng, egnb, 128, 2048, 32, flagI);

    // 1x1 head convs + sigmoid -> output
    head_out_k<<<dim3(16), blk, 0, stream>>>(t1s, t1e, s2w, s2b, e2w, e2b, d_out, flagI);
}

// Round 9
// 475.378 us; speedup vs baseline: 1.2998x; 1.2579x over previous
//
#include <hip/hip_runtime.h>
#include <hip/hip_bf16.h>

typedef __hip_bfloat16 bf16;

static __device__ __forceinline__ float b2f(bf16 v) { return __bfloat162float(v); }

// flag-aware input load: bf==1 -> bf16, bf==0 -> f32
static __device__ __forceinline__ float ldin(const void* p, long i, int bf) {
    return bf ? b2f(((const bf16*)p)[i]) : ((const float*)p)[i];
}

// ---------------- dtype detect ----------------
__global__ void detect_k(const unsigned short* __restrict__ x16, int* __restrict__ flag) {
    __shared__ int cnt[256];
    unsigned short u = x16[threadIdx.x];
    int e = (u >> 7) & 0xFF;
    cnt[threadIdx.x] = (e >= 100 && e <= 140) ? 1 : 0;
    __syncthreads();
    for (int off = 128; off > 0; off >>= 1) {
        if (threadIdx.x < off) cnt[threadIdx.x] += cnt[threadIdx.x + off];
        __syncthreads();
    }
    if (threadIdx.x == 0) *flag = (cnt[0] > 217) ? 1 : 0;
}

// ---------------- transposes ----------------
__global__ void transpose_w_k(const void* __restrict__ in, float* __restrict__ out,
                              int M, int K, const int* __restrict__ flagp) {
    int bf = *flagp;
    int idx = blockIdx.x * 256 + threadIdx.x;
    if (idx >= M * K) return;
    int k = idx / M, m = idx - k * M;
    out[idx] = ldin(in, (long)m * K + k, bf);
}

// out[(n*256 + c)*512 + h3] = w3[(h3*256 + c)*32 + n]
__global__ void transpose_w3_k(const void* __restrict__ w3, float* __restrict__ out,
                               const int* __restrict__ flagp) {
    int bf = *flagp;
    int bid = blockIdx.x;            // 2048 = 8 h3-tiles * 256 c
    int h30 = (bid & 7) * 64;
    int c = bid >> 3;
    __shared__ float tile[64][33];
    int tid = threadIdx.x;
    for (int i = tid; i < 64 * 32; i += 256) {
        int hl = i >> 5, n = i & 31;
        tile[hl][n] = ldin(w3, ((long)(h30 + hl) * 256 + c) * 32 + n, bf);
    }
    __syncthreads();
    for (int i = tid; i < 64 * 32; i += 256) {
        int n = i >> 6, hl = i & 63;
        out[((long)n * 256 + c) * 512 + h30 + hl] = tile[hl][n];
    }
}

// ---------------- im2col ----------------
__global__ void im2col_x_k(const void* __restrict__ x, float* __restrict__ colx,
                           const int* __restrict__ flagp) {
    int bf = *flagp;
    int idx = blockIdx.x * 256 + threadIdx.x;   // 786432
    if (idx >= 786432) return;
    int t = idx & 255;
    int b = idx / 393216;
    int k = (idx - b * 393216) >> 8;
    int c = k / 3, q = k - c * 3;
    int tt = t + q - 1;
    colx[idx] = (tt >= 0 && tt < 256) ? ldin(x, ((long)b * 512 + c) * 256 + tt, bf) : 0.f;
}

__global__ void im2col_f_k(const float* __restrict__ f, float* __restrict__ col) {
    int idx = blockIdx.x * 256 + threadIdx.x;   // 4718592
    if (idx >= 4718592) return;
    int p = idx & 2047;
    int rem = idx >> 11;
    int b = rem / 1152;
    int k = rem - b * 1152;
    int c = k / 9, q = k - c * 9;
    int dy = q / 3, dx = q - dy * 3;
    int t = p >> 3, w = p & 7;
    int tt = t + dy - 1, ww = w + dx - 1;
    col[idx] = (tt >= 0 && tt < 256 && ww >= 0 && ww < 8)
                   ? f[((long)b * 128 + c) * 2048 + tt * 8 + ww] : 0.f;
}

// ---------------- generic tiled GEMM w/ register prefetch (64x64, 4x4) ----------------
// accum: 0 = C[idx]=acc+bias ; 1 = C[ks*sstride+idx]=acc (split buffer, no bias) ;
//        2 = C[idx]+=acc (plain RMW, single writer)
template<int BM, int BP, int TM, int TP>
__global__ __launch_bounds__(256) void gemm_t(
    const float* __restrict__ A, const float* __restrict__ B, float* __restrict__ C,
    const void* __restrict__ bias, const void* __restrict__ bias2,
    int M, int K, int P, int az_mod, int bz_div,
    long a_zs, long b_zs, long c_zs1, long c_zs2, int c_ms,
    int zmod, int ksplit, long sstride, int accum, const int* __restrict__ flagp)
{
    int bf = *flagp;
    int zraw = blockIdx.z;
    int z = zraw % zmod;
    int ks = zraw / zmod;
    int klen = K / ksplit;
    int kbeg = ks * klen;
    int kend = kbeg + klen;
    int za = z % az_mod;
    const float* A2 = A + (long)za * a_zs;
    const float* B2 = B + (long)(z / bz_div) * b_zs;
    float* C2 = C + (long)(z / bz_div) * c_zs1 + (long)za * c_zs2;
    const void* bi = (bias2 != nullptr && za != 0) ? bias2 : bias;

    __shared__ float As[16][BM];
    __shared__ float Bs[16][BP];
    int tid = threadIdx.x;
    int ty = tid >> 4, tx = tid & 15;
    int lk = tid >> 4;
    int lma = (tid & 15) * TM;
    int lpb = (tid & 15) * TP;
    int m0 = blockIdx.y * BM, p0 = blockIdx.x * BP;

    float acc[TM][TP];
    #pragma unroll
    for (int i = 0; i < TM; ++i)
        #pragma unroll
        for (int j = 0; j < TP; ++j) acc[i][j] = 0.f;

    float ra[TM], rb[TP];
    {
        const float* ap = A2 + (long)(kbeg + lk) * M + m0 + lma;
        const float* bp = B2 + (long)(kbeg + lk) * P + p0 + lpb;
        #pragma unroll
        for (int u = 0; u < TM; ++u) ra[u] = ap[u];
        #pragma unroll
        for (int u = 0; u < TP; ++u) rb[u] = bp[u];
    }

    for (int kc = kbeg; kc < kend; kc += 16) {
        #pragma unroll
        for (int u = 0; u < TM; ++u) As[lk][lma + u] = ra[u];
        #pragma unroll
        for (int u = 0; u < TP; ++u) Bs[lk][lpb + u] = rb[u];
        __syncthreads();
        if (kc + 16 < kend) {
            const float* ap = A2 + (long)(kc + 16 + lk) * M + m0 + lma;
            const float* bp = B2 + (long)(kc + 16 + lk) * P + p0 + lpb;
            #pragma unroll
            for (int u = 0; u < TM; ++u) ra[u] = ap[u];
            #pragma unroll
            for (int u = 0; u < TP; ++u) rb[u] = bp[u];
        }
        #pragma unroll
        for (int kk = 0; kk < 16; ++kk) {
            float av[TM], bv[TP];
            #pragma unroll
            for (int i = 0; i < TM; ++i) av[i] = As[kk][ty * TM + i];
            #pragma unroll
            for (int j = 0; j < TP; ++j) bv[j] = Bs[kk][tx * TP + j];
            #pragma unroll
            for (int i = 0; i < TM; ++i)
                #pragma unroll
                for (int j = 0; j < TP; ++j)
                    acc[i][j] += av[i] * bv[j];
        }
        __syncthreads();
    }

    #pragma unroll
    for (int i = 0; i < TM; ++i) {
        int m = m0 + ty * TM + i;
        float bb = bi ? ldin(bi, m, bf) : 0.f;
        #pragma unroll
        for (int j = 0; j < TP; ++j) {
            long idx = (long)m * c_ms + p0 + tx * TP + j;
            if (accum == 1) C2[sstride * ks + idx] = acc[i][j];
            else if (accum == 2) C2[idx] += acc[i][j];
            else C2[idx] = acc[i][j] + bb;
        }
    }
}

// ---------------- 128x128 quad GEMM: 8x8/thread as 2x2 quadrants of 4x4 ----------------
// All LDS access is stride-4-float b128 (2-way bank aliasing = free); no conflicts.
__global__ __launch_bounds__(256) void gemm_q(
    const float* __restrict__ A, const float* __restrict__ B, float* __restrict__ C,
    const void* __restrict__ bias, const void* __restrict__ bias2,
    int M, int K, int P, int az_mod, int bz_div,
    long a_zs, long b_zs, long c_zs1, long c_zs2, int c_ms,
    int zmod, int ksplit, long sstride, int accum, const int* __restrict__ flagp)
{
    int bf = *flagp;
    int zraw = blockIdx.z;
    int z = zraw % zmod;
    int ks = zraw / zmod;
    int klen = K / ksplit;
    int kbeg = ks * klen, kend = kbeg + klen;
    int za = z % az_mod;
    const float* A2 = A + (long)za * a_zs;
    const float* B2 = B + (long)(z / bz_div) * b_zs;
    float* C2 = C + (long)(z / bz_div) * c_zs1 + (long)za * c_zs2;
    const void* bi = (bias2 != nullptr && za != 0) ? bias2 : bias;

    __shared__ float As[16][128];
    __shared__ float Bs[16][128];
    int tid = threadIdx.x;
    int ty = tid >> 4, tx = tid & 15;   // 16x16 thread grid
    int lk = tid >> 4;
    int lc4 = (tid & 15) * 4;
    int m0 = blockIdx.y * 128, p0 = blockIdx.x * 128;

    float acc[8][8];
    #pragma unroll
    for (int i = 0; i < 8; ++i)
        #pragma unroll
        for (int j = 0; j < 8; ++j) acc[i][j] = 0.f;

    float4 ra0, ra1, rb0, rb1;
    {
        const float* ap = A2 + (long)(kbeg + lk) * M + m0 + lc4;
        const float* bp = B2 + (long)(kbeg + lk) * P + p0 + lc4;
        ra0 = *(const float4*)ap;  ra1 = *(const float4*)(ap + 64);
        rb0 = *(const float4*)bp;  rb1 = *(const float4*)(bp + 64);
    }

    for (int kc = kbeg; kc < kend; kc += 16) {
        *(float4*)&As[lk][lc4]      = ra0;
        *(float4*)&As[lk][64 + lc4] = ra1;
        *(float4*)&Bs[lk][lc4]      = rb0;
        *(float4*)&Bs[lk][64 + lc4] = rb1;
        __syncthreads();
        if (kc + 16 < kend) {
            const float* ap = A2 + (long)(kc + 16 + lk) * M + m0 + lc4;
            const float* bp = B2 + (long)(kc + 16 + lk) * P + p0 + lc4;
            ra0 = *(const float4*)ap;  ra1 = *(const float4*)(ap + 64);
            rb0 = *(const float4*)bp;  rb1 = *(const float4*)(bp + 64);
        }
        #pragma unroll
        for (int kk = 0; kk < 16; ++kk) {
            float4 av0 = *(float4*)&As[kk][ty * 4];
            float4 av1 = *(float4*)&As[kk][64 + ty * 4];
            float4 bv0 = *(float4*)&Bs[kk][tx * 4];
            float4 bv1 = *(float4*)&Bs[kk][64 + tx * 4];
            float av[8] = {av0.x, av0.y, av0.z, av0.w, av1.x, av1.y, av1.z, av1.w};
            float bv[8] = {bv0.x, bv0.y, bv0.z, bv0.w, bv1.x, bv1.y, bv1.z, bv1.w};
            #pragma unroll
            for (int i = 0; i < 8; ++i)
                #pragma unroll
                for (int j = 0; j < 8; ++j)
                    acc[i][j] += av[i] * bv[j];
        }
        __syncthreads();
    }

    #pragma unroll
    for (int r = 0; r < 2; ++r)
        #pragma unroll
        for (int i = 0; i < 4; ++i) {
            int m = m0 + r * 64 + ty * 4 + i;
            float bb = bi ? ldin(bi, m, bf) : 0.f;
            #pragma unroll
            for (int c = 0; c < 2; ++c)
                #pragma unroll
                for (int j = 0; j < 4; ++j) {
                    long idx = (long)m * c_ms + p0 + c * 64 + tx * 4 + j;
                    float v = acc[r * 4 + i][c * 4 + j];
                    if (accum == 1) C2[sstride * ks + idx] = v;
                    else if (accum == 2) C2[idx] += v;
                    else C2[idx] = v + bb;
                }
        }
}

// ---------------- split-buffer reduction (+bias) ----------------
// out[e..e+3] = bias(e) + sum_s bufs[s*sstride + e..e+3]
__global__ void reduce_k(const float* __restrict__ bufs, float* __restrict__ out,
                         int n4, int ns, long sstride, const void* __restrict__ b1,
                         const void* __restrict__ b2, int rshift, int cshift, int cmask,
                         const int* __restrict__ flagp)
{
    int bf = *flagp;
    int i = blockIdx.x * 256 + threadIdx.x;
    if (i >= n4) return;
    long e = (long)i * 4;
    float4 s = *(const float4*)(bufs + e);
    for (int k = 1; k < ns; ++k) {
        float4 v = *(const float4*)(bufs + (long)k * sstride + e);
        s.x += v.x; s.y += v.y; s.z += v.z; s.w += v.w;
    }
    const void* bp = (rshift >= 0 && ((e >> rshift) & 3) >= 2) ? b2 : b1;
    int c = (int)((e >> cshift) & cmask);
    float bb = ldin(bp, c, bf);
    *(float4*)(out + e) = make_float4(s.x + bb, s.y + bb, s.z + bb, s.w + bb);
}

// ---------------- GroupNorm (in place) + ReLU ----------------
__global__ __launch_bounds__(1024) void gn_relu_k(
    float* __restrict__ buf, const void* __restrict__ g, const void* __restrict__ bt,
    int C, int S, int groups, const int* __restrict__ flagp)
{
    int bf = *flagp;
    int nt = blockDim.x;
    int gid = blockIdx.x;
    int b = gid / groups, gr = gid % groups;
    int cpg = C / groups;
    long cnt = (long)cpg * S;
    float* base = buf + ((long)b * C + (long)gr * cpg) * S;
    double s = 0.0, s2 = 0.0;
    for (long i = threadIdx.x; i < cnt; i += nt) {
        float v = base[i];
        s += v; s2 += (double)v * v;
    }
    __shared__ double rs[1024], rq[1024];
    rs[threadIdx.x] = s; rq[threadIdx.x] = s2;
    __syncthreads();
    for (int off = nt >> 1; off > 0; off >>= 1) {
        if (threadIdx.x < off) { rs[threadIdx.x] += rs[threadIdx.x + off]; rq[threadIdx.x] += rq[threadIdx.x + off]; }
        __syncthreads();
    }
    double mean_d = rs[0] / (double)cnt;
    float mean = (float)mean_d;
    float var = (float)(rq[0] / (double)cnt - mean_d * mean_d);
    float rstd = rsqrtf(var + 1e-5f);
    for (long i = threadIdx.x; i < cnt; i += nt) {
        int c = gr * cpg + (int)(i / S);
        float v = (base[i] - mean) * rstd * ldin(g, c, bf) + ldin(bt, c, bf);
        base[i] = v > 0.f ? v : 0.f;
    }
}

// ---------------- sparse mask table ----------------
__global__ __launch_bounds__(384) void build_table_k(
    const void* __restrict__ mask, int* __restrict__ tabd,
    float* __restrict__ tabw, const int* __restrict__ flagp)
{
    int bf = *flagp;
    int nw = blockIdx.x;            // == w*32 + n (table base index)
    int w = nw >> 5, n = nw & 31;
    int tid = threadIdx.x;          // 0..383 ; d = tid-165 valid while d<=165
    int d = tid - 165;
    float v = 0.f;
    if (d <= 165) {
        if (d < 0) v = ldin(mask, (long)(254 + d) * 65536 + ((long)n * 256 + 254) * 8 + w, bf);
        else       v = ldin(mask, (long)(1 + d) * 65536 + ((long)n * 256 + 1) * 8 + w, bf);
    }
    __shared__ unsigned char nz[384];
    nz[tid] = (v != 0.f) ? 1 : 0;
    if (tid < 6) { tabd[nw * 6 + tid] = 0; tabw[nw * 6 + tid] = 0.f; }
    __syncthreads();
    if (v != 0.f) {
        int slot = 0;
        for (int j = 0; j < tid; ++j) slot += nz[j];
        if (slot < 6) { tabd[nw * 6 + slot] = d; tabw[nw * 6 + slot] = v; }
    }
}

__global__ void build_corr_k(const void* __restrict__ mask, const int* __restrict__ tabd,
                             const float* __restrict__ tabw, float* __restrict__ corrB,
                             const int* __restrict__ flagp) {
    int bf = *flagp;
    int idx = blockIdx.x * 256 + threadIdx.x;   // 65536
    if (idx >= 65536) return;
    int n = idx >> 11, p = idx & 2047;
    int t = p >> 3, w = p & 7;
    float mv = ldin(mask, ((long)n * 256 + t) * 8 + w, bf);
    float sub = 0.f;
    int base = (w * 32 + n) * 6;
    for (int k = 0; k < 6; ++k)
        if (tabd[base + k] == -t && tabw[base + k] != 0.f) sub += tabw[base + k];
    corrB[idx] = mv - sub;
}

// p0t[(b*32+n)*512 + h3] = P[b][h3][n][0]
__global__ void p0t_k(const float* __restrict__ P, float* __restrict__ p0t) {
    int idx = blockIdx.x * 256 + threadIdx.x;   // 32768
    if (idx >= 32768) return;
    int h3 = idx & 511, n = (idx >> 9) & 31, b = idx >> 14;
    p0t[idx] = P[(((long)(b * 512 + h3) * 32) + n) * 256];
}

// y[b][h3][t*8+w] = r3b[h3] + sum_{n,k} wt * P[b][h3][n][t+delta]
__global__ __launch_bounds__(256) void apply_y_k(
    const float* __restrict__ P, const int* __restrict__ tabd,
    const float* __restrict__ tabw, const void* __restrict__ r3b,
    float* __restrict__ y, const int* __restrict__ flagp)
{
    int bf = *flagp;
    int h3 = blockIdx.x;                 // 0..511
    __shared__ float Pl[2 * 8192];       // 64 KB: b=0 rows then b=1 rows
    __shared__ float4 Tp4[768];          // 12 KB packed (wt,d) pairs
    const float4* p04 = (const float4*)(P + (long)h3 * 8192);
    const float4* p14 = (const float4*)(P + (512L + h3) * 8192);
    float4* pl4 = (float4*)Pl;
    for (int i = threadIdx.x; i < 2048; i += 256) {
        pl4[i] = p04[i];
        pl4[i + 2048] = p14[i];
    }
    float2* tp2 = (float2*)Tp4;
    for (int i = threadIdx.x; i < 1536; i += 256)
        tp2[i] = make_float2(tabw[i], __int_as_float(tabd[i]));
    __syncthreads();

    int t = threadIdx.x;
    float a0[8], a1[8];
    #pragma unroll
    for (int w = 0; w < 8; ++w) { a0[w] = 0.f; a1[w] = 0.f; }

    #pragma unroll 1
    for (int n = 0; n < 32; ++n) {
        const float* Pn0 = Pl + (n << 8);
        #pragma unroll
        for (int w = 0; w < 8; ++w) {
            int e4 = ((w << 5) + n) * 3;     // 6 float2 = 3 float4
            float4 q0 = Tp4[e4], q1 = Tp4[e4 + 1], q2 = Tp4[e4 + 2];
            float wts[6] = {q0.x, q0.z, q1.x, q1.z, q2.x, q2.z};
            int   dss[6] = {__float_as_int(q0.y), __float_as_int(q0.w),
                            __float_as_int(q1.y), __float_as_int(q1.w),
                            __float_as_int(q2.y), __float_as_int(q2.w)};
            #pragma unroll
            for (int k = 0; k < 6; ++k) {
                int tau = t + dss[k];
                int idx = tau & 255;
                float wt = ((unsigned)tau < 256u) ? wts[k] : 0.f;
                a0[w] += wt * Pn0[idx];
                a1[w] += wt * Pn0[idx + 8192];
            }
        }
    }

    float bias = ldin(r3b, h3, bf);
    long y0 = (long)h3 * 2048 + (long)t * 8;
    long y1 = y0 + 512L * 2048;
    *(float4*)(y + y0)     = make_float4(a0[0] + bias, a0[1] + bias, a0[2] + bias, a0[3] + bias);
    *(float4*)(y + y0 + 4) = make_float4(a0[4] + bias, a0[5] + bias, a0[6] + bias, a0[7] + bias);
    *(float4*)(y + y1)     = make_float4(a1[0] + bias, a1[1] + bias, a1[2] + bias, a1[3] + bias);
    *(float4*)(y + y1 + 4) = make_float4(a1[4] + bias, a1[5] + bias, a1[6] + bias, a1[7] + bias);
}

__global__ void head_out_k(const float* __restrict__ t1s, const float* __restrict__ t1e,
                           const void* __restrict__ s2w, const void* __restrict__ s2b,
                           const void* __restrict__ e2w, const void* __restrict__ e2b,
                           void* __restrict__ out, const int* __restrict__ flagp) {
    int bf = *flagp;
    int idx = blockIdx.x * 256 + threadIdx.x;   // 4096
    if (idx >= 4096) return;
    int b = idx >> 11, p = idx & 2047;
    const float* ts = t1s + (long)b * 262144 + p;
    const float* te = t1e + (long)b * 262144 + p;
    float as = ldin(s2b, 0, bf), ae = ldin(e2b, 0, bf);
    #pragma unroll 8
    for (int c = 0; c < 128; ++c) {
        as += ldin(s2w, c, bf) * ts[(long)c * 2048];
        ae += ldin(e2w, c, bf) * te[(long)c * 2048];
    }
    float vs = 1.f / (1.f + expf(-as));
    float ve = 1.f / (1.f + expf(-ae));
    long o0 = ((long)b * 2) * 2048 + p;
    long o1 = ((long)b * 2 + 1) * 2048 + p;
    if (bf) {
        ((bf16*)out)[o0] = __float2bfloat16(vs);
        ((bf16*)out)[o1] = __float2bfloat16(ve);
    } else {
        ((float*)out)[o0] = vs;
        ((float*)out)[o1] = ve;
    }
}

// ---------------- launch ----------------
extern "C" void kernel_launch(void* const* d_in, const int* in_sizes, int n_in,
                              void* d_out, int out_size, void* d_ws, size_t ws_size,
                              hipStream_t stream) {
    const void* x    = d_in[0];
    const void* mask = d_in[1];
    const void* c1w  = d_in[2];
    const void* c1b  = d_in[3];
    const void* gn1g = d_in[4];
    const void* gn1b = d_in[5];
    const void* w3   = d_in[6];
    const void* r3b  = d_in[7];
    const void* gn3g = d_in[8];
    const void* gn3b = d_in[9];
    const void* w2   = d_in[10];
    const void* r2b  = d_in[11];
    const void* gn2g = d_in[12];
    const void* gn2b = d_in[13];
    const void* s1w  = d_in[14];
    const void* s1b  = d_in[15];
    const void* sgng = d_in[16];
    const void* sgnb = d_in[17];
    const void* s2w  = d_in[18];
    const void* s2b  = d_in[19];
    const void* e1w  = d_in[20];
    const void* e1b  = d_in[21];
    const void* egng = d_in[22];
    const void* egnb = d_in[23];
    const void* e2w  = d_in[24];
    const void* e2b  = d_in[25];
    float* ws = (float*)d_ws;

    // layout (floats); dead-region aliasing per pipeline timeline
    int*   flagI = (int*)(ws + 0);       // 64 reserved
    float* h     = ws + 64;              // 131072
    float* c1t   = ws + 131136;          // 393216
    float* w2t   = ws + 524352;          // 65536
    float* s1t   = ws + 589888;          // 147456
    float* e1t   = ws + 737344;          // 147456 (adjacent to s1t)
    float* corrB = ws + 884800;          // 65536
    float* tabw  = ws + 950336;          // 1536
    int*   tabd  = (int*)(ws + 951872);  // 1536
    float* p0t   = ws + 953408;          // 32768
    float* t1s   = ws + 986176;          // 524288
    float* t1e   = ws + 1510464;         // 524288 (adjacent to t1s)
    float* f     = ws + 2034752;         // 524288
    float* y     = ws + 2559040;         // 2097152
    float* w3t   = ws + 4656192;         // 4194304
    float* Pb    = ws + 8850496;         // 8388608  (total ~69 MB)
    float* colx  = Pb;                   // alias: dead before Pb written
    float* col   = Pb;                   // alias: Pb dead before col written
    float* bufs_c1 = y;                  // 8 x 131072  (y dead until apply_y)
    float* bufs_r2 = Pb;                 // 4 x 524288  (Pb dead after p0t; before col)
    float* bufs_hd = y;                  // 6 x 1048576 spans y+w3t (both dead by heads GEMM)

    dim3 blk(256);
    dim3 blkG(1024);

    detect_k<<<dim3(1), blk, 0, stream>>>((const unsigned short*)x, flagI);

    // weight transposes + table extraction
    transpose_w_k<<<dim3(1536), blk, 0, stream>>>(c1w, c1t, 256, 1536, flagI);
    transpose_w_k<<<dim3(256),  blk, 0, stream>>>(w2,  w2t, 128, 512, flagI);
    transpose_w_k<<<dim3(576),  blk, 0, stream>>>(s1w, s1t, 128, 1152, flagI);
    transpose_w_k<<<dim3(576),  blk, 0, stream>>>(e1w, e1t, 128, 1152, flagI);
    transpose_w3_k<<<dim3(2048), blk, 0, stream>>>(w3, w3t, flagI);
    build_table_k<<<dim3(256), dim3(384), 0, stream>>>(mask, tabd, tabw, flagI);
    build_corr_k<<<dim3(256), blk, 0, stream>>>(mask, tabd, tabw, corrB, flagI);

    // conv1: im2col + split-K(8) GEMM into buffers + reduce(+bias) + GN1 + ReLU
    im2col_x_k<<<dim3(3072), blk, 0, stream>>>(x, colx, flagI);
    gemm_t<64,64,4,4><<<dim3(4,4,16), blk, 0, stream>>>(
        c1t, colx, bufs_c1, nullptr, nullptr, 256, 1536, 256,
        1, 1, 0L, 393216L, 65536L, 0L, 256, 2, 8, 131072L, 1, flagI);
    reduce_k<<<dim3(128), blk, 0, stream>>>(bufs_c1, h, 32768, 8, 131072L,
                                            c1b, nullptr, -1, 8, 255, flagI);
    gn_relu_k<<<dim3(64), blkG, 0, stream>>>(h, gn1g, gn1b, 256, 256, 32, flagI);

    // P[b,h3,n,tau] = sum_c w3[h3,c,n] h[b,c,tau]  (128x128 quad tile, direct store)
    gemm_q<<<dim3(2,4,64), blk, 0, stream>>>(
        w3t, h, Pb, nullptr, nullptr, 512, 256, 256,
        32, 32, 131072L, 65536L, 4194304L, 256L, 8192, 64, 1, 0L, 0, flagI);

    // sparse mask apply + bin-0 correction (plain RMW, single writer) + GN3 + ReLU
    apply_y_k<<<dim3(512), blk, 0, stream>>>(Pb, tabd, tabw, r3b, y, flagI);
    p0t_k<<<dim3(128), blk, 0, stream>>>(Pb, p0t);
    gemm_t<64,64,4,4><<<dim3(32,8,2), blk, 0, stream>>>(
        p0t, corrB, y, nullptr, nullptr, 512, 32, 2048,
        2, 1, 16384L, 0L, 0L, 1048576L, 2048, 2, 1, 0L, 2, flagI);
    gn_relu_k<<<dim3(64), blkG, 0, stream>>>(y, gn3g, gn3b, 512, 2048, 32, flagI);

    // r2d 1x1: split-K(4) GEMM into buffers + reduce(+bias) + GN2 + ReLU
    gemm_t<64,64,4,4><<<dim3(32,2,8), blk, 0, stream>>>(
        w2t, y, bufs_r2, nullptr, nullptr, 128, 512, 2048,
        1, 1, 0L, 1048576L, 262144L, 0L, 2048, 2, 4, 524288L, 1, flagI);
    reduce_k<<<dim3(512), blk, 0, stream>>>(bufs_r2, f, 131072, 4, 524288L,
                                            r2b, nullptr, -1, 11, 127, flagI);
    gn_relu_k<<<dim3(64), blkG, 0, stream>>>(f, gn2g, gn2b, 128, 2048, 32, flagI);

    // heads: shared im2col + split-K(6) quad GEMM into buffers + reduce(+bias) + GN + ReLU
    im2col_f_k<<<dim3(18432), blk, 0, stream>>>(f, col);
    gemm_q<<<dim3(16,1,24), blk, 0, stream>>>(
        s1t, col, bufs_hd, nullptr, nullptr, 128, 1152, 2048,
        2, 2, 147456L, 2359296L, 262144L, 524288L, 2048, 4, 6, 1048576L, 1, flagI);
    reduce_k<<<dim3(1024), blk, 0, stream>>>(bufs_hd, t1s, 262144, 6, 1048576L,
                                             s1b, e1b, 18, 11, 127, flagI);
    gn_relu_k<<<dim3(64), blkG, 0, stream>>>(t1s, sgng, sgnb, 128, 2048, 32, flagI);
    gn_relu_k<<<dim3(64), blkG, 0, stream>>>(t1e, egng, egnb, 128, 2048, 32, flagI);

    // 1x1 head convs + sigmoid -> output
    head_out_k<<<dim3(16), blk, 0, stream>>>(t1s, t1e, s2w, s2b, e2w, e2b, d_out, flagI);
}

// Round 10
// 461.604 us; speedup vs baseline: 1.3386x; 1.0298x over previous
//
#include <hip/hip_runtime.h>
#include <hip/hip_bf16.h>

typedef __hip_bfloat16 bf16;
typedef __attribute__((ext_vector_type(8))) short short8;
typedef __attribute__((ext_vector_type(4))) float f32x4;

static __device__ __forceinline__ float b2f(bf16 v) { return __bfloat162float(v); }

// flag-aware input load: bf==1 -> bf16, bf==0 -> f32
static __device__ __forceinline__ float ldin(const void* p, long i, int bf) {
    return bf ? b2f(((const bf16*)p)[i]) : ((const float*)p)[i];
}

// ---------------- dtype detect ----------------
__global__ void detect_k(const unsigned short* __restrict__ x16, int* __restrict__ flag) {
    __shared__ int cnt[256];
    unsigned short u = x16[threadIdx.x];
    int e = (u >> 7) & 0xFF;
    cnt[threadIdx.x] = (e >= 100 && e <= 140) ? 1 : 0;
    __syncthreads();
    for (int off = 128; off > 0; off >>= 1) {
        if (threadIdx.x < off) cnt[threadIdx.x] += cnt[threadIdx.x + off];
        __syncthreads();
    }
    if (threadIdx.x == 0) *flag = (cnt[0] > 217) ? 1 : 0;
}

// ---------------- transposes ----------------
__global__ void transpose_w_k(const void* __restrict__ in, float* __restrict__ out,
                              int M, int K, const int* __restrict__ flagp) {
    int bf = *flagp;
    int idx = blockIdx.x * 256 + threadIdx.x;
    if (idx >= M * K) return;
    int k = idx / M, m = idx - k * M;
    out[idx] = ldin(in, (long)m * K + k, bf);
}

// w3b[n][h3][c] (bf16) from w3[(h3*256+c)*32+n]
__global__ __launch_bounds__(256) void transpose_w3b_k(const void* __restrict__ w3,
                                                       bf16* __restrict__ out,
                                                       const int* __restrict__ flagp) {
    int bf = *flagp;
    int h3 = blockIdx.x;     // 512
    __shared__ bf16 t[8192];
    long base = (long)h3 * 8192;
    for (int i = threadIdx.x; i < 8192; i += 256)
        t[i] = __float2bfloat16(ldin(w3, base + i, bf));   // exact when input is bf16
    __syncthreads();
    for (int i = threadIdx.x; i < 8192; i += 256) {
        int n = i >> 8, c = i & 255;
        out[((long)n * 512 + h3) * 256 + c] = t[c * 32 + n];
    }
}

// hbT[b][tau][c] (bf16) from h[b][c][tau] (fp32)
__global__ void cast_hT_k(const float* __restrict__ h, bf16* __restrict__ out) {
    int idx = blockIdx.x * 256 + threadIdx.x;   // 131072
    if (idx >= 131072) return;
    int b = idx >> 16, r = idx & 65535;
    int tau = r >> 8, c = r & 255;
    out[idx] = __float2bfloat16(h[b * 65536 + c * 256 + tau]);
}

// ---------------- im2col ----------------
__global__ void im2col_x_k(const void* __restrict__ x, float* __restrict__ colx,
                           const int* __restrict__ flagp) {
    int bf = *flagp;
    int idx = blockIdx.x * 256 + threadIdx.x;   // 786432
    if (idx >= 786432) return;
    int t = idx & 255;
    int b = idx / 393216;
    int k = (idx - b * 393216) >> 8;
    int c = k / 3, q = k - c * 3;
    int tt = t + q - 1;
    colx[idx] = (tt >= 0 && tt < 256) ? ldin(x, ((long)b * 512 + c) * 256 + tt, bf) : 0.f;
}

__global__ void im2col_f_k(const float* __restrict__ f, float* __restrict__ col) {
    int idx = blockIdx.x * 256 + threadIdx.x;   // 4718592
    if (idx >= 4718592) return;
    int p = idx & 2047;
    int rem = idx >> 11;
    int b = rem / 1152;
    int k = rem - b * 1152;
    int c = k / 9, q = k - c * 9;
    int dy = q / 3, dx = q - dy * 3;
    int t = p >> 3, w = p & 7;
    int tt = t + dy - 1, ww = w + dx - 1;
    col[idx] = (tt >= 0 && tt < 256 && ww >= 0 && ww < 8)
                   ? f[((long)b * 128 + c) * 2048 + tt * 8 + ww] : 0.f;
}

// ---------------- MFMA P-GEMM ----------------
// P[b, h3, n, tau] = sum_c w3[h3,c,n] * h[b,c,tau]   (bf16 x bf16 -> fp32)
// A = w3b[n][h3][c]; B = hbT[b][tau][c]; grid (1, 8, 64), 256 thr (4 waves).
// Wave handles 16-row h3-strip x full tau(256) x full K(256).
__global__ __launch_bounds__(256) void pgemm_mfma(
    const bf16* __restrict__ w3b, const bf16* __restrict__ hbT,
    float* __restrict__ P)
{
    int z = blockIdx.z;          // b*32 + n
    int b = z >> 5, n = z & 31;
    int bm = blockIdx.y;         // 0..7 (h3 64-strip)
    int tid = threadIdx.x;
    int wv = tid >> 6, lane = tid & 63;
    int q = lane >> 4, col = lane & 15;

    f32x4 acc[16];
    #pragma unroll
    for (int i = 0; i < 16; ++i) acc[i] = (f32x4){0.f, 0.f, 0.f, 0.f};

    // A fragment: lane holds A[m = col][k = q*8 + j]
    const short8* Abase = (const short8*)(w3b + ((long)n * 512 + bm * 64 + wv * 16 + col) * 256);
    const short8* Bbase = (const short8*)(hbT + (long)b * 65536);

    #pragma unroll
    for (int kc = 0; kc < 8; ++kc) {
        short8 af = Abase[kc * 4 + q];
        #pragma unroll
        for (int nt = 0; nt < 16; ++nt) {
            // B fragment: lane holds B[k = q*8+j][n-col = col] ; hbT row = tau
            short8 bfr = Bbase[(nt * 16 + col) * 32 + kc * 4 + q];
            acc[nt] = __builtin_amdgcn_mfma_f32_16x16x32_bf16(af, bfr, acc[nt], 0, 0, 0);
        }
    }

    // D: lane holds D[row = q*4+r][col] ; Pb[b*4194304 + h3*8192 + n*256 + tau]
    long dbase = (long)b * 4194304 + (long)n * 256 +
                 (long)(bm * 64 + wv * 16 + q * 4) * 8192 + col;
    #pragma unroll
    for (int nt = 0; nt < 16; ++nt)
        #pragma unroll
        for (int r = 0; r < 4; ++r)
            P[dbase + (long)r * 8192 + nt * 16] = acc[nt][r];
}

// ---------------- generic tiled GEMM w/ register prefetch (64x64, 4x4) ----------------
template<int BM, int BP, int TM, int TP>
__global__ __launch_bounds__(256) void gemm_t(
    const float* __restrict__ A, const float* __restrict__ B, float* __restrict__ C,
    const void* __restrict__ bias, const void* __restrict__ bias2,
    int M, int K, int P, int az_mod, int bz_div,
    long a_zs, long b_zs, long c_zs1, long c_zs2, int c_ms,
    int zmod, int ksplit, long sstride, int accum, const int* __restrict__ flagp)
{
    int bf = *flagp;
    int zraw = blockIdx.z;
    int z = zraw % zmod;
    int ks = zraw / zmod;
    int klen = K / ksplit;
    int kbeg = ks * klen;
    int kend = kbeg + klen;
    int za = z % az_mod;
    const float* A2 = A + (long)za * a_zs;
    const float* B2 = B + (long)(z / bz_div) * b_zs;
    float* C2 = C + (long)(z / bz_div) * c_zs1 + (long)za * c_zs2;
    const void* bi = (bias2 != nullptr && za != 0) ? bias2 : bias;

    __shared__ float As[16][BM];
    __shared__ float Bs[16][BP];
    int tid = threadIdx.x;
    int ty = tid >> 4, tx = tid & 15;
    int lk = tid >> 4;
    int lma = (tid & 15) * TM;
    int lpb = (tid & 15) * TP;
    int m0 = blockIdx.y * BM, p0 = blockIdx.x * BP;

    float acc[TM][TP];
    #pragma unroll
    for (int i = 0; i < TM; ++i)
        #pragma unroll
        for (int j = 0; j < TP; ++j) acc[i][j] = 0.f;

    float ra[TM], rb[TP];
    {
        const float* ap = A2 + (long)(kbeg + lk) * M + m0 + lma;
        const float* bp = B2 + (long)(kbeg + lk) * P + p0 + lpb;
        #pragma unroll
        for (int u = 0; u < TM; ++u) ra[u] = ap[u];
        #pragma unroll
        for (int u = 0; u < TP; ++u) rb[u] = bp[u];
    }

    for (int kc = kbeg; kc < kend; kc += 16) {
        #pragma unroll
        for (int u = 0; u < TM; ++u) As[lk][lma + u] = ra[u];
        #pragma unroll
        for (int u = 0; u < TP; ++u) Bs[lk][lpb + u] = rb[u];
        __syncthreads();
        if (kc + 16 < kend) {
            const float* ap = A2 + (long)(kc + 16 + lk) * M + m0 + lma;
            const float* bp = B2 + (long)(kc + 16 + lk) * P + p0 + lpb;
            #pragma unroll
            for (int u = 0; u < TM; ++u) ra[u] = ap[u];
            #pragma unroll
            for (int u = 0; u < TP; ++u) rb[u] = bp[u];
        }
        #pragma unroll
        for (int kk = 0; kk < 16; ++kk) {
            float av[TM], bv[TP];
            #pragma unroll
            for (int i = 0; i < TM; ++i) av[i] = As[kk][ty * TM + i];
            #pragma unroll
            for (int j = 0; j < TP; ++j) bv[j] = Bs[kk][tx * TP + j];
            #pragma unroll
            for (int i = 0; i < TM; ++i)
                #pragma unroll
                for (int j = 0; j < TP; ++j)
                    acc[i][j] += av[i] * bv[j];
        }
        __syncthreads();
    }

    #pragma unroll
    for (int i = 0; i < TM; ++i) {
        int m = m0 + ty * TM + i;
        float bb = bi ? ldin(bi, m, bf) : 0.f;
        #pragma unroll
        for (int j = 0; j < TP; ++j) {
            long idx = (long)m * c_ms + p0 + tx * TP + j;
            if (accum == 1) C2[sstride * ks + idx] = acc[i][j];
            else if (accum == 2) C2[idx] += acc[i][j];
            else C2[idx] = acc[i][j] + bb;
        }
    }
}

// ---------------- 128x128 quad GEMM: 8x8/thread as 2x2 quadrants of 4x4 ----------------
__global__ __launch_bounds__(256) void gemm_q(
    const float* __restrict__ A, const float* __restrict__ B, float* __restrict__ C,
    const void* __restrict__ bias, const void* __restrict__ bias2,
    int M, int K, int P, int az_mod, int bz_div,
    long a_zs, long b_zs, long c_zs1, long c_zs2, int c_ms,
    int zmod, int ksplit, long sstride, int accum, const int* __restrict__ flagp)
{
    int bf = *flagp;
    int zraw = blockIdx.z;
    int z = zraw % zmod;
    int ks = zraw / zmod;
    int klen = K / ksplit;
    int kbeg = ks * klen, kend = kbeg + klen;
    int za = z % az_mod;
    const float* A2 = A + (long)za * a_zs;
    const float* B2 = B + (long)(z / bz_div) * b_zs;
    float* C2 = C + (long)(z / bz_div) * c_zs1 + (long)za * c_zs2;
    const void* bi = (bias2 != nullptr && za != 0) ? bias2 : bias;

    __shared__ float As[16][128];
    __shared__ float Bs[16][128];
    int tid = threadIdx.x;
    int ty = tid >> 4, tx = tid & 15;
    int lk = tid >> 4;
    int lc4 = (tid & 15) * 4;
    int m0 = blockIdx.y * 128, p0 = blockIdx.x * 128;

    float acc[8][8];
    #pragma unroll
    for (int i = 0; i < 8; ++i)
        #pragma unroll
        for (int j = 0; j < 8; ++j) acc[i][j] = 0.f;

    float4 ra0, ra1, rb0, rb1;
    {
        const float* ap = A2 + (long)(kbeg + lk) * M + m0 + lc4;
        const float* bp = B2 + (long)(kbeg + lk) * P + p0 + lc4;
        ra0 = *(const float4*)ap;  ra1 = *(const float4*)(ap + 64);
        rb0 = *(const float4*)bp;  rb1 = *(const float4*)(bp + 64);
    }

    for (int kc = kbeg; kc < kend; kc += 16) {
        *(float4*)&As[lk][lc4]      = ra0;
        *(float4*)&As[lk][64 + lc4] = ra1;
        *(float4*)&Bs[lk][lc4]      = rb0;
        *(float4*)&Bs[lk][64 + lc4] = rb1;
        __syncthreads();
        if (kc + 16 < kend) {
            const float* ap = A2 + (long)(kc + 16 + lk) * M + m0 + lc4;
            const float* bp = B2 + (long)(kc + 16 + lk) * P + p0 + lc4;
            ra0 = *(const float4*)ap;  ra1 = *(const float4*)(ap + 64);
            rb0 = *(const float4*)bp;  rb1 = *(const float4*)(bp + 64);
        }
        #pragma unroll
        for (int kk = 0; kk < 16; ++kk) {
            float4 av0 = *(float4*)&As[kk][ty * 4];
            float4 av1 = *(float4*)&As[kk][64 + ty * 4];
            float4 bv0 = *(float4*)&Bs[kk][tx * 4];
            float4 bv1 = *(float4*)&Bs[kk][64 + tx * 4];
            float av[8] = {av0.x, av0.y, av0.z, av0.w, av1.x, av1.y, av1.z, av1.w};
            float bv[8] = {bv0.x, bv0.y, bv0.z, bv0.w, bv1.x, bv1.y, bv1.z, bv1.w};
            #pragma unroll
            for (int i = 0; i < 8; ++i)
                #pragma unroll
                for (int j = 0; j < 8; ++j)
                    acc[i][j] += av[i] * bv[j];
        }
        __syncthreads();
    }

    #pragma unroll
    for (int r = 0; r < 2; ++r)
        #pragma unroll
        for (int i = 0; i < 4; ++i) {
            int m = m0 + r * 64 + ty * 4 + i;
            float bb = bi ? ldin(bi, m, bf) : 0.f;
            #pragma unroll
            for (int c = 0; c < 2; ++c)
                #pragma unroll
                for (int j = 0; j < 4; ++j) {
                    long idx = (long)m * c_ms + p0 + c * 64 + tx * 4 + j;
                    float v = acc[r * 4 + i][c * 4 + j];
                    if (accum == 1) C2[sstride * ks + idx] = v;
                    else if (accum == 2) C2[idx] += v;
                    else C2[idx] = v + bb;
                }
        }
}

// ---------------- split-buffer reduction (+bias) ----------------
__global__ void reduce_k(const float* __restrict__ bufs, float* __restrict__ out,
                         int n4, int ns, long sstride, const void* __restrict__ b1,
                         const void* __restrict__ b2, int rshift, int cshift, int cmask,
                         const int* __restrict__ flagp)
{
    int bf = *flagp;
    int i = blockIdx.x * 256 + threadIdx.x;
    if (i >= n4) return;
    long e = (long)i * 4;
    float4 s = *(const float4*)(bufs + e);
    for (int k = 1; k < ns; ++k) {
        float4 v = *(const float4*)(bufs + (long)k * sstride + e);
        s.x += v.x; s.y += v.y; s.z += v.z; s.w += v.w;
    }
    const void* bp = (rshift >= 0 && ((e >> rshift) & 3) >= 2) ? b2 : b1;
    int c = (int)((e >> cshift) & cmask);
    float bb = ldin(bp, c, bf);
    *(float4*)(out + e) = make_float4(s.x + bb, s.y + bb, s.z + bb, s.w + bb);
}

// ---------------- GroupNorm (in place) + ReLU ----------------
__global__ __launch_bounds__(1024) void gn_relu_k(
    float* __restrict__ buf, const void* __restrict__ g, const void* __restrict__ bt,
    int C, int S, int groups, const int* __restrict__ flagp)
{
    int bf = *flagp;
    int nt = blockDim.x;
    int gid = blockIdx.x;
    int b = gid / groups, gr = gid % groups;
    int cpg = C / groups;
    long cnt = (long)cpg * S;
    float* base = buf + ((long)b * C + (long)gr * cpg) * S;
    double s = 0.0, s2 = 0.0;
    for (long i = threadIdx.x; i < cnt; i += nt) {
        float v = base[i];
        s += v; s2 += (double)v * v;
    }
    __shared__ double rs[1024], rq[1024];
    rs[threadIdx.x] = s; rq[threadIdx.x] = s2;
    __syncthreads();
    for (int off = nt >> 1; off > 0; off >>= 1) {
        if (threadIdx.x < off) { rs[threadIdx.x] += rs[threadIdx.x + off]; rq[threadIdx.x] += rq[threadIdx.x + off]; }
        __syncthreads();
    }
    double mean_d = rs[0] / (double)cnt;
    float mean = (float)mean_d;
    float var = (float)(rq[0] / (double)cnt - mean_d * mean_d);
    float rstd = rsqrtf(var + 1e-5f);
    for (long i = threadIdx.x; i < cnt; i += nt) {
        int c = gr * cpg + (int)(i / S);
        float v = (base[i] - mean) * rstd * ldin(g, c, bf) + ldin(bt, c, bf);
        base[i] = v > 0.f ? v : 0.f;
    }
}

// ---------------- sparse mask table ----------------
__global__ __launch_bounds__(384) void build_table_k(
    const void* __restrict__ mask, int* __restrict__ tabd,
    float* __restrict__ tabw, const int* __restrict__ flagp)
{
    int bf = *flagp;
    int nw = blockIdx.x;
    int w = nw >> 5, n = nw & 31;
    int tid = threadIdx.x;
    int d = tid - 165;
    float v = 0.f;
    if (d <= 165) {
        if (d < 0) v = ldin(mask, (long)(254 + d) * 65536 + ((long)n * 256 + 254) * 8 + w, bf);
        else       v = ldin(mask, (long)(1 + d) * 65536 + ((long)n * 256 + 1) * 8 + w, bf);
    }
    __shared__ unsigned char nz[384];
    nz[tid] = (v != 0.f) ? 1 : 0;
    if (tid < 6) { tabd[nw * 6 + tid] = 0; tabw[nw * 6 + tid] = 0.f; }
    __syncthreads();
    if (v != 0.f) {
        int slot = 0;
        for (int j = 0; j < tid; ++j) slot += nz[j];
        if (slot < 6) { tabd[nw * 6 + slot] = d; tabw[nw * 6 + slot] = v; }
    }
}

__global__ void build_corr_k(const void* __restrict__ mask, const int* __restrict__ tabd,
                             const float* __restrict__ tabw, float* __restrict__ corrB,
                             const int* __restrict__ flagp) {
    int bf = *flagp;
    int idx = blockIdx.x * 256 + threadIdx.x;   // 65536
    if (idx >= 65536) return;
    int n = idx >> 11, p = idx & 2047;
    int t = p >> 3, w = p & 7;
    float mv = ldin(mask, ((long)n * 256 + t) * 8 + w, bf);
    float sub = 0.f;
    int base = (w * 32 + n) * 6;
    for (int k = 0; k < 6; ++k)
        if (tabd[base + k] == -t && tabw[base + k] != 0.f) sub += tabw[base + k];
    corrB[idx] = mv - sub;
}

// p0t[(b*32+n)*512 + h3] = P[b][h3][n][0]
__global__ void p0t_k(const float* __restrict__ P, float* __restrict__ p0t) {
    int idx = blockIdx.x * 256 + threadIdx.x;   // 32768
    if (idx >= 32768) return;
    int h3 = idx & 511, n = (idx >> 9) & 31, b = idx >> 14;
    p0t[idx] = P[(((long)(b * 512 + h3) * 32) + n) * 256];
}

// y[b][h3][t*8+w] = r3b[h3] + sum_{n,k} wt * P[b][h3][n][t+delta]
__global__ __launch_bounds__(256) void apply_y_k(
    const float* __restrict__ P, const int* __restrict__ tabd,
    const float* __restrict__ tabw, const void* __restrict__ r3b,
    float* __restrict__ y, const int* __restrict__ flagp)
{
    int bf = *flagp;
    int h3 = blockIdx.x;                 // 0..511
    __shared__ float Pl[2 * 8192];
    __shared__ float4 Tp4[768];
    const float4* p04 = (const float4*)(P + (long)h3 * 8192);
    const float4* p14 = (const float4*)(P + (512L + h3) * 8192);
    float4* pl4 = (float4*)Pl;
    for (int i = threadIdx.x; i < 2048; i += 256) {
        pl4[i] = p04[i];
        pl4[i + 2048] = p14[i];
    }
    float2* tp2 = (float2*)Tp4;
    for (int i = threadIdx.x; i < 1536; i += 256)
        tp2[i] = make_float2(tabw[i], __int_as_float(tabd[i]));
    __syncthreads();

    int t = threadIdx.x;
    float a0[8], a1[8];
    #pragma unroll
    for (int w = 0; w < 8; ++w) { a0[w] = 0.f; a1[w] = 0.f; }

    #pragma unroll 1
    for (int n = 0; n < 32; ++n) {
        const float* Pn0 = Pl + (n << 8);
        #pragma unroll
        for (int w = 0; w < 8; ++w) {
            int e4 = ((w << 5) + n) * 3;
            float4 q0 = Tp4[e4], q1 = Tp4[e4 + 1], q2 = Tp4[e4 + 2];
            float wts[6] = {q0.x, q0.z, q1.x, q1.z, q2.x, q2.z};
            int   dss[6] = {__float_as_int(q0.y), __float_as_int(q0.w),
                            __float_as_int(q1.y), __float_as_int(q1.w),
                            __float_as_int(q2.y), __float_as_int(q2.w)};
            #pragma unroll
            for (int k = 0; k < 6; ++k) {
                int tau = t + dss[k];
                int idx = tau & 255;
                float wt = ((unsigned)tau < 256u) ? wts[k] : 0.f;
                a0[w] += wt * Pn0[idx];
                a1[w] += wt * Pn0[idx + 8192];
            }
        }
    }

    float bias = ldin(r3b, h3, bf);
    long y0 = (long)h3 * 2048 + (long)t * 8;
    long y1 = y0 + 512L * 2048;
    *(float4*)(y + y0)     = make_float4(a0[0] + bias, a0[1] + bias, a0[2] + bias, a0[3] + bias);
    *(float4*)(y + y0 + 4) = make_float4(a0[4] + bias, a0[5] + bias, a0[6] + bias, a0[7] + bias);
    *(float4*)(y + y1)     = make_float4(a1[0] + bias, a1[1] + bias, a1[2] + bias, a1[3] + bias);
    *(float4*)(y + y1 + 4) = make_float4(a1[4] + bias, a1[5] + bias, a1[6] + bias, a1[7] + bias);
}

__global__ void head_out_k(const float* __restrict__ t1s, const float* __restrict__ t1e,
                           const void* __restrict__ s2w, const void* __restrict__ s2b,
                           const void* __restrict__ e2w, const void* __restrict__ e2b,
                           void* __restrict__ out, const int* __restrict__ flagp) {
    int bf = *flagp;
    int idx = blockIdx.x * 256 + threadIdx.x;   // 4096
    if (idx >= 4096) return;
    int b = idx >> 11, p = idx & 2047;
    const float* ts = t1s + (long)b * 262144 + p;
    const float* te = t1e + (long)b * 262144 + p;
    float as = ldin(s2b, 0, bf), ae = ldin(e2b, 0, bf);
    #pragma unroll 8
    for (int c = 0; c < 128; ++c) {
        as += ldin(s2w, c, bf) * ts[(long)c * 2048];
        ae += ldin(e2w, c, bf) * te[(long)c * 2048];
    }
    float vs = 1.f / (1.f + expf(-as));
    float ve = 1.f / (1.f + expf(-ae));
    long o0 = ((long)b * 2) * 2048 + p;
    long o1 = ((long)b * 2 + 1) * 2048 + p;
    if (bf) {
        ((bf16*)out)[o0] = __float2bfloat16(vs);
        ((bf16*)out)[o1] = __float2bfloat16(ve);
    } else {
        ((float*)out)[o0] = vs;
        ((float*)out)[o1] = ve;
    }
}

// ---------------- launch ----------------
extern "C" void kernel_launch(void* const* d_in, const int* in_sizes, int n_in,
                              void* d_out, int out_size, void* d_ws, size_t ws_size,
                              hipStream_t stream) {
    const void* x    = d_in[0];
    const void* mask = d_in[1];
    const void* c1w  = d_in[2];
    const void* c1b  = d_in[3];
    const void* gn1g = d_in[4];
    const void* gn1b = d_in[5];
    const void* w3   = d_in[6];
    const void* r3b  = d_in[7];
    const void* gn3g = d_in[8];
    const void* gn3b = d_in[9];
    const void* w2   = d_in[10];
    const void* r2b  = d_in[11];
    const void* gn2g = d_in[12];
    const void* gn2b = d_in[13];
    const void* s1w  = d_in[14];
    const void* s1b  = d_in[15];
    const void* sgng = d_in[16];
    const void* sgnb = d_in[17];
    const void* s2w  = d_in[18];
    const void* s2b  = d_in[19];
    const void* e1w  = d_in[20];
    const void* e1b  = d_in[21];
    const void* egng = d_in[22];
    const void* egnb = d_in[23];
    const void* e2w  = d_in[24];
    const void* e2b  = d_in[25];
    float* ws = (float*)d_ws;

    // layout (floats); dead-region aliasing per pipeline timeline
    int*   flagI = (int*)(ws + 0);       // 64 reserved
    float* h     = ws + 64;              // 131072
    float* c1t   = ws + 131136;          // 393216
    float* w2t   = ws + 524352;          // 65536
    float* s1t   = ws + 589888;          // 147456
    float* e1t   = ws + 737344;          // 147456 (adjacent to s1t)
    float* corrB = ws + 884800;          // 65536
    float* tabw  = ws + 950336;          // 1536
    int*   tabd  = (int*)(ws + 951872);  // 1536
    float* p0t   = ws + 953408;          // 32768
    float* t1s   = ws + 986176;          // 524288
    float* t1e   = ws + 1510464;         // 524288 (adjacent to t1s)
    float* f     = ws + 2034752;         // 524288
    float* y     = ws + 2559040;         // 2097152
    float* w3reg = ws + 4656192;         // 4194304 (bf16 buffers live here)
    float* Pb    = ws + 8850496;         // 8388608  (total ~69 MB)
    bf16*  w3b   = (bf16*)w3reg;                   // 4194304 bf16 = 2097152 floats
    bf16*  hbT   = (bf16*)(w3reg + 2097152);       // 131072 bf16 = 65536 floats
    float* colx  = Pb;                   // alias: dead before Pb written
    float* col   = Pb;                   // alias: Pb dead before col written
    float* bufs_c1 = y;                  // 8 x 131072  (y dead until apply_y)
    float* bufs_r2 = Pb;                 // 4 x 524288  (Pb dead after p0t; before col)
    float* bufs_hd = y;                  // 6 x 1048576 spans y+w3reg (both dead by heads GEMM)

    dim3 blk(256);
    dim3 blkG(1024);

    detect_k<<<dim3(1), blk, 0, stream>>>((const unsigned short*)x, flagI);

    // weight transposes + table extraction
    transpose_w_k<<<dim3(1536), blk, 0, stream>>>(c1w, c1t, 256, 1536, flagI);
    transpose_w_k<<<dim3(256),  blk, 0, stream>>>(w2,  w2t, 128, 512, flagI);
    transpose_w_k<<<dim3(576),  blk, 0, stream>>>(s1w, s1t, 128, 1152, flagI);
    transpose_w_k<<<dim3(576),  blk, 0, stream>>>(e1w, e1t, 128, 1152, flagI);
    transpose_w3b_k<<<dim3(512), blk, 0, stream>>>(w3, w3b, flagI);
    build_table_k<<<dim3(256), dim3(384), 0, stream>>>(mask, tabd, tabw, flagI);
    build_corr_k<<<dim3(256), blk, 0, stream>>>(mask, tabd, tabw, corrB, flagI);

    // conv1: im2col + split-K(8) GEMM into buffers + reduce(+bias) + GN1 + ReLU
    im2col_x_k<<<dim3(3072), blk, 0, stream>>>(x, colx, flagI);
    gemm_t<64,64,4,4><<<dim3(4,4,16), blk, 0, stream>>>(
        c1t, colx, bufs_c1, nullptr, nullptr, 256, 1536, 256,
        1, 1, 0L, 393216L, 65536L, 0L, 256, 2, 8, 131072L, 1, flagI);
    reduce_k<<<dim3(128), blk, 0, stream>>>(bufs_c1, h, 32768, 8, 131072L,
                                            c1b, nullptr, -1, 8, 255, flagI);
    gn_relu_k<<<dim3(64), blkG, 0, stream>>>(h, gn1g, gn1b, 256, 256, 32, flagI);

    // P-GEMM via bf16 MFMA: cast h -> hbT, then pgemm_mfma
    cast_hT_k<<<dim3(512), blk, 0, stream>>>(h, hbT);
    pgemm_mfma<<<dim3(1, 8, 64), blk, 0, stream>>>(w3b, hbT, Pb);

    // sparse mask apply + bin-0 correction (plain RMW, single writer) + GN3 + ReLU
    apply_y_k<<<dim3(512), blk, 0, stream>>>(Pb, tabd, tabw, r3b, y, flagI);
    p0t_k<<<dim3(128), blk, 0, stream>>>(Pb, p0t);
    gemm_t<64,64,4,4><<<dim3(32,8,2), blk, 0, stream>>>(
        p0t, corrB, y, nullptr, nullptr, 512, 32, 2048,
        2, 1, 16384L, 0L, 0L, 1048576L, 2048, 2, 1, 0L, 2, flagI);
    gn_relu_k<<<dim3(64), blkG, 0, stream>>>(y, gn3g, gn3b, 512, 2048, 32, flagI);

    // r2d 1x1: split-K(4) GEMM into buffers + reduce(+bias) + GN2 + ReLU
    gemm_t<64,64,4,4><<<dim3(32,2,8), blk, 0, stream>>>(
        w2t, y, bufs_r2, nullptr, nullptr, 128, 512, 2048,
        1, 1, 0L, 1048576L, 262144L, 0L, 2048, 2, 4, 524288L, 1, flagI);
    reduce_k<<<dim3(512), blk, 0, stream>>>(bufs_r2, f, 131072, 4, 524288L,
                                            r2b, nullptr, -1, 11, 127, flagI);
    gn_relu_k<<<dim3(64), blkG, 0, stream>>>(f, gn2g, gn2b, 128, 2048, 32, flagI);

    // heads: shared im2col + split-K(6) quad GEMM into buffers + reduce(+bias) + GN + ReLU
    im2col_f_k<<<dim3(18432), blk, 0, stream>>>(f, col);
    gemm_q<<<dim3(16,1,24), blk, 0, stream>>>(
        s1t, col, bufs_hd, nullptr, nullptr, 128, 1152, 2048,
        2, 2, 147456L, 2359296L, 262144L, 524288L, 2048, 4, 6, 1048576L, 1, flagI);
    reduce_k<<<dim3(1024), blk, 0, stream>>>(bufs_hd, t1s, 262144, 6, 1048576L,
                                             s1b, e1b, 18, 11, 127, flagI);
    gn_relu_k<<<dim3(64), blkG, 0, stream>>>(t1s, sgng, sgnb, 128, 2048, 32, flagI);
    gn_relu_k<<<dim3(64), blkG, 0, stream>>>(t1e, egng, egnb, 128, 2048, 32, flagI);

    // 1x1 head convs + sigmoid -> output
    head_out_k<<<dim3(16), blk, 0, stream>>>(t1s, t1e, s2w, s2b, e2w, e2b, d_out, flagI);
}